// Round 17
// baseline (307.302 us; speedup 1.0000x reference)
//
#include <hip/hip_runtime.h>
#include <hip/hip_fp16.h>
#include <stdint.h>

#define B_ 2
#define C_ 96
#define D_ 24
#define H_ 56
#define W_ 56
#define E_ 384
#define HW_ (H_*W_)        // 3136
#define S_ (D_*HW_)        // 75264
#define N_ (B_*S_)         // 150528
#define NBLK_ 2352         // N_/64 (k2 blocks)
#define WS2BLK_ 24576      // shorts per 64-pos block in fragment-ordered ws2

typedef __attribute__((ext_vector_type(8))) short bf16x8;
typedef __attribute__((ext_vector_type(4))) float f32x4;
typedef __fp16 fp16x2 __attribute__((ext_vector_type(2)));

static __device__ __forceinline__ float bf2f(unsigned short h){
    union { unsigned int u; float f; } v; v.u = ((unsigned int)h) << 16; return v.f;
}
static __device__ __forceinline__ unsigned short f2bf(float x){
    union { float f; unsigned int u; } v; v.f = x;
    unsigned int r = v.u + 0x7FFFu + ((v.u >> 16) & 1u);
    return (unsigned short)(r >> 16);
}
static __device__ __forceinline__ __half2 u2h2(unsigned int u){
    union { unsigned int u; __half2 h; } v; v.u = u; return v.h;
}
static __device__ __forceinline__ unsigned int pk_f16(float a, float b){
    union { fp16x2 h; unsigned int u; } v;
    v.h = __builtin_amdgcn_cvt_pkrtz(a, b);
    return v.u;
}
// fast GELU: v*sigmoid(1.5957691*(v+0.044715 v^3)) via exp2, max |err| ~3e-4
static __device__ __forceinline__ float gelu_f(float v){
    float v2 = v*v;
    float arg = v * fmaf(v2, -0.1029432f, -2.3022080f);
    return v / (1.f + exp2f(arg));
}

// ---------------- K1 v5: 12d x 8h x 56w tile, 384 threads, 2 d-out/thread -------
// halo 18x14x62 staged fp16 (pitch 72, 36.3KB LDS -> 4 blocks/CU = 24 waves).
// weights = packed half2(w,w) GLOBAL table, wave-uniform -> s_load.
__global__ __launch_bounds__(384) void k1_dwconv(
    const float* __restrict__ x, const unsigned int* __restrict__ pkwg,
    const float* __restrict__ bias, unsigned short* __restrict__ ws1)
{
    __shared__ __align__(16) unsigned short hl[18*14*72];
    const int dt = blockIdx.x / 7;   // 0..1
    const int ht = blockIdx.x - dt*7;// 0..6
    const int c  = blockIdx.y, b = blockIdx.z;
    const int d0 = dt*12, h0 = ht*8;
    const int tid = threadIdx.x;
    const float* xc = x + (size_t)(b*C_ + c) * S_;
    const unsigned int* pw = pkwg + c*343;   // block-uniform -> s_load

    for (int i = tid; i < 18*14*31; i += 384){
        int sidx = i / (14*31);
        int rem  = i - sidx*(14*31);
        int hr   = rem / 31;
        int wp   = rem - hr*31;
        int d = d0 - 3 + sidx, h = h0 - 3 + hr, w = wp*2 - 3;
        bool ok = (unsigned)d < D_ && (unsigned)h < H_;
        float v0 = (ok && (unsigned)w     < W_) ? xc[d*HW_ + h*W_ + w]   : 0.f;
        float v1 = (ok && (unsigned)(w+1) < W_) ? xc[d*HW_ + h*W_ + w+1] : 0.f;
        *(unsigned int*)&hl[(sidx*14 + hr)*72 + wp*2] = pk_f16(v0, v1);
    }
    __syncthreads();

    const int wz = tid & 7, hz = (tid >> 3) & 7, dz = tid >> 6;  // dz 0..5
    if (wz >= 7) return;

    __half2 acc0[4], acc1[4];
    #pragma unroll
    for (int r=0;r<4;++r){ acc0[r] = u2h2(0u); acc1[r] = u2h2(0u); }

    for (int kh = 0; kh < 7; ++kh){
        unsigned int wprev[7];
        for (int si = 0; si < 8; ++si){
            const unsigned short* rp = &hl[((dz*2 + si)*14 + hz + kh)*72 + wz*8];
            uint4 wa = *(const uint4*)rp;
            uint2 wb = *(const uint2*)(rp + 8);
            unsigned int wcq = *(const unsigned int*)(rp + 12);
            unsigned int W[7] = {wa.x, wa.y, wa.z, wa.w, wb.x, wb.y, wcq};
            unsigned int Sh[6];
            #pragma unroll
            for (int m=0;m<6;++m) Sh[m] = __builtin_amdgcn_alignbit(W[m+1], W[m], 16);

            if (si < 7){
                unsigned int wcur[7];
                #pragma unroll
                for (int k=0;k<7;++k) wcur[k] = pw[si*49 + kh*7 + k];
                #pragma unroll
                for (int kw=0; kw<7; ++kw){
                    const int m = kw >> 1;
                    __half2 wp = u2h2(wcur[kw]);
                    #pragma unroll
                    for (int r=0;r<4;++r){
                        __half2 src = (kw & 1) ? u2h2(Sh[m+r]) : u2h2(W[m+r]);
                        acc0[r] = __hfma2(src, wp, acc0[r]);
                    }
                }
                if (si > 0){
                    #pragma unroll
                    for (int kw=0; kw<7; ++kw){
                        const int m = kw >> 1;
                        __half2 wp = u2h2(wprev[kw]);
                        #pragma unroll
                        for (int r=0;r<4;++r){
                            __half2 src = (kw & 1) ? u2h2(Sh[m+r]) : u2h2(W[m+r]);
                            acc1[r] = __hfma2(src, wp, acc1[r]);
                        }
                    }
                }
                #pragma unroll
                for (int k=0;k<7;++k) wprev[k] = wcur[k];
            } else {
                #pragma unroll
                for (int kw=0; kw<7; ++kw){
                    const int m = kw >> 1;
                    __half2 wp = u2h2(wprev[kw]);
                    #pragma unroll
                    for (int r=0;r<4;++r){
                        __half2 src = (kw & 1) ? u2h2(Sh[m+r]) : u2h2(W[m+r]);
                        acc1[r] = __hfma2(src, wp, acc1[r]);
                    }
                }
            }
        }
    }

    const float bs = bias[c];
    float o0v[8], o1v[8];
    #pragma unroll
    for (int r=0;r<4;++r){
        o0v[2*r]   = __low2float(acc0[r])  + bs;
        o0v[2*r+1] = __high2float(acc0[r]) + bs;
        o1v[2*r]   = __low2float(acc1[r])  + bs;
        o1v[2*r+1] = __high2float(acc1[r]) + bs;
    }
    size_t o0 = (size_t)(b*C_ + c)*S_ + (size_t)(d0 + dz*2)*HW_ + (h0 + hz)*W_ + wz*8;
    unsigned int p0 = (unsigned)f2bf(o0v[0]) | ((unsigned)f2bf(o0v[1])<<16);
    unsigned int p1 = (unsigned)f2bf(o0v[2]) | ((unsigned)f2bf(o0v[3])<<16);
    unsigned int p2 = (unsigned)f2bf(o0v[4]) | ((unsigned)f2bf(o0v[5])<<16);
    unsigned int p3 = (unsigned)f2bf(o0v[6]) | ((unsigned)f2bf(o0v[7])<<16);
    *(uint4*)&ws1[o0] = make_uint4(p0,p1,p2,p3);
    p0 = (unsigned)f2bf(o1v[0]) | ((unsigned)f2bf(o1v[1])<<16);
    p1 = (unsigned)f2bf(o1v[2]) | ((unsigned)f2bf(o1v[3])<<16);
    p2 = (unsigned)f2bf(o1v[4]) | ((unsigned)f2bf(o1v[5])<<16);
    p3 = (unsigned)f2bf(o1v[6]) | ((unsigned)f2bf(o1v[7])<<16);
    *(uint4*)&ws1[o0 + HW_] = make_uint4(p0,p1,p2,p3);
}

// ---------- kw1t: w1 transpose to bf16 + dw-weight fp16x2 pack table ------------
__global__ __launch_bounds__(256) void kw1t(
    const float* __restrict__ w1, const float* __restrict__ wk,
    unsigned short* __restrict__ w1t, unsigned int* __restrict__ pkwg)
{
    int idx = blockIdx.x*256 + threadIdx.x;
    if (idx < E_*C_){
        int e = idx / C_, c = idx % C_;
        w1t[idx] = f2bf(w1[c*E_ + e]);
    }
    if (idx < 96*343){
        unsigned short us = __half_as_ushort(__float2half(wk[idx]));
        pkwg[idx] = (unsigned)us | ((unsigned)us << 16);
    }
}

// ------------- K2: LN + pwconv1(MFMA) + GELU -> ws2 (fragment-ordered) ----------
// ws2[blk][q][nt][r][lane]: store instr = 64 lanes x 2B contiguous (128B dense).
__global__ __launch_bounds__(256) void k2_ln_pw1(
    const unsigned short* __restrict__ ws1, const float* __restrict__ ln_w,
    const float* __restrict__ ln_b, const unsigned short* __restrict__ w1t,
    const float* __restrict__ b1, unsigned short* __restrict__ ws2,
    float* __restrict__ partial)
{
    __shared__ unsigned short ly[64*104];
    __shared__ float red1[256], red2[256];
    __shared__ float smu[64], srs[64];
    __shared__ float sq[4][384];
    __shared__ float b1s[384];
    const int tid = threadIdx.x;
    const int p = tid & 63, q = tid >> 6;
    const int n0 = blockIdx.x * 64;
    const int b = n0 / S_;
    const int s0 = n0 - b*S_;
    const size_t basein = (size_t)(b*C_)*S_ + s0 + p;

    for (int i = tid; i < 384; i += 256) b1s[i] = b1[i];

    float v[24];
    float sum=0.f, ssq=0.f;
    #pragma unroll
    for (int i=0;i<24;++i){
        int c = q*24 + i;
        float t = bf2f(ws1[basein + (size_t)c*S_]);
        v[i] = t; sum += t; ssq = fmaf(t,t,ssq);
    }
    red1[tid]=sum; red2[tid]=ssq;
    __syncthreads();
    if (q==0){
        float s1 = red1[p]+red1[64+p]+red1[128+p]+red1[192+p];
        float s2 = red2[p]+red2[64+p]+red2[128+p]+red2[192+p];
        float mu = s1 * (1.f/96.f);
        float var = s2*(1.f/96.f) - mu*mu;
        smu[p]=mu; srs[p]=rsqrtf(var + 1e-6f);
    }
    __syncthreads();
    {
        float mu = smu[p], rs = srs[p];
        #pragma unroll
        for (int i=0;i<24;++i){
            int c = q*24+i;
            ly[p*104 + c] = f2bf((v[i]-mu)*rs*ln_w[c] + ln_b[c]);
        }
    }
    __syncthreads();

    const int lane = tid & 63;
    const int lr = lane & 15;
    const int lk = lane >> 4;
    bf16x8 af[3];
    #pragma unroll
    for (int kk=0;kk<3;++kk)
        af[kk] = *(const bf16x8*)&ly[(q*16 + lr)*104 + kk*32 + lk*8];

    unsigned short* wout = ws2 + (size_t)blockIdx.x*WS2BLK_ + q*6144 + lane;

    for (int nt=0; nt<24; ++nt){
        f32x4 acc = {0.f,0.f,0.f,0.f};
        #pragma unroll
        for (int kk=0;kk<3;++kk){
            bf16x8 bfr = *(const bf16x8*)&w1t[(size_t)(nt*16 + lr)*C_ + kk*32 + lk*8];
            acc = __builtin_amdgcn_mfma_f32_16x16x32_bf16(af[kk], bfr, acc, 0, 0, 0);
        }
        float bias = b1s[nt*16 + lr];
        float ps = 0.f;
        #pragma unroll
        for (int r=0;r<4;++r){
            float val = acc[r] + bias;
            float g = gelu_f(val);
            ps = fmaf(g,g,ps);
            wout[nt*256 + r*64] = f2bf(g);
        }
        ps += __shfl_xor(ps, 16);
        ps += __shfl_xor(ps, 32);
        if (lane < 16) sq[q][nt*16 + lane] = ps;
    }
    __syncthreads();
    // transposed partial: [e][NBLK_]; 2 scattered 4B stores per thread (L2-merged)
    for (int i = tid; i < 384; i += 256)
        partial[(size_t)i*NBLK_ + blockIdx.x] = sq[0][i]+sq[1][i]+sq[2][i]+sq[3][i];
}

// ---------- K3a1: parallel reduce partial[e][NBLK_] -> gx2[b][e] ----------------
// grid (48,2): block handles 8 e-rows; 32 lanes per e, contiguous float4 reads.
__global__ __launch_bounds__(256) void k3a1(
    const float* __restrict__ partial, float* __restrict__ gx2)
{
    const int g = blockIdx.x, b = blockIdx.y;
    const int t = threadIdx.x;
    const int el = t >> 5, lane = t & 31;
    const int e = g*8 + el;
    const float4* row = (const float4*)(partial + (size_t)e*NBLK_ + b*(NBLK_/2));
    float s = 0.f;
    for (int k = lane; k < 294; k += 32){
        float4 v = row[k];
        s += v.x + v.y + v.z + v.w;
    }
    s += __shfl_xor(s, 16);
    s += __shfl_xor(s, 8);
    s += __shfl_xor(s, 4);
    s += __shfl_xor(s, 2);
    s += __shfl_xor(s, 1);
    if (lane == 0) gx2[b*E_ + e] = s;
}

// ---------- K3a2: gx2 -> GRN scale sscale[b][e] ---------------------------------
__global__ __launch_bounds__(384) void k3a2(
    const float* __restrict__ gx2, const float* __restrict__ gamma,
    float* __restrict__ sscale)
{
    const int b = blockIdx.x, e = threadIdx.x;
    float s = fmaxf(gx2[b*E_ + e], 0.f);    // NaN insurance
    float g = sqrtf(s);
    float vsum = g;
    #pragma unroll
    for (int off=32; off; off>>=1) vsum += __shfl_down(vsum, off);
    __shared__ float r[6];
    __shared__ float mean_s;
    if ((e & 63)==0) r[e>>6] = vsum;
    __syncthreads();
    if (e==0) mean_s = (r[0]+r[1]+r[2]+r[3]+r[4]+r[5]) * (1.f/384.f);
    __syncthreads();
    sscale[b*E_ + e] = 1.f + gamma[e] * (g / (mean_s + 1e-6f));
}

// ---------- kw2s: parallel w2s[b][c][e] = w2[e][c]*sscale[b][e] ------------------
__global__ __launch_bounds__(256) void kw2s(
    const float* __restrict__ w2, const float* __restrict__ sscale,
    unsigned short* __restrict__ w2s)
{
    int idx = blockIdx.x*256 + threadIdx.x;   // 288 blocks x 256 = 73728
    int b = idx / (C_*E_);
    int rem = idx - b*(C_*E_);
    int c = rem / E_, e = rem - (rem/E_)*E_;
    w2s[idx] = f2bf(w2[e*C_ + c] * sscale[b*E_ + e]);
}

// ---------- k3c: bc[j] = b2[j] + sum_e beta[e]*w2[e,j], 96 parallel blocks ------
__global__ __launch_bounds__(64) void k3c_bc(
    const float* __restrict__ b2, const float* __restrict__ beta,
    const float* __restrict__ w2, float* __restrict__ bc)
{
    const int j = blockIdx.x, lane = threadIdx.x;
    float a = 0.f;
    #pragma unroll
    for (int r=0;r<6;++r){
        int e = lane*6 + r;
        a = fmaf(beta[e], w2[e*C_ + j], a);
    }
    #pragma unroll
    for (int off=32; off; off>>=1) a += __shfl_down(a, off);
    if (lane==0) bc[j] = b2[j] + a;
}

// ---------- K4: pwconv2 (MFMA), fragment-ordered ws2 reads ----------------------
__global__ __launch_bounds__(256) void k4_pw2(
    const unsigned short* __restrict__ ws2, const unsigned short* __restrict__ w2s,
    const float* __restrict__ bc, const float* __restrict__ x,
    float* __restrict__ out)
{
    const int tid = threadIdx.x;
    const int n0 = blockIdx.x * 128;
    const int b = n0 / S_;
    const int s0 = n0 - b*S_;
    const int lane = tid & 63, q = tid >> 6;
    const int lr = lane & 15, lk = lane >> 4;

    f32x4 acc0[6], acc1[6];
    #pragma unroll
    for (int m=0;m<6;++m){ acc0[m] = (f32x4){0,0,0,0}; acc1[m] = (f32x4){0,0,0,0}; }
    const unsigned short* w2sb = w2s + (size_t)b*C_*E_;
    // fragment-ordered ws2: lane offset within block
    const unsigned short* base0 = ws2 + (size_t)(blockIdx.x*2)*WS2BLK_
                                + q*6144 + (lr&3)*64 + (lr>>2)*16 + (lk&1)*8;

    for (int kk=0; kk<12; ++kk){
        const int off = (2*kk + (lk>>1))*256;
        bf16x8 bfr0 = *(const bf16x8*)&base0[off];
        bf16x8 bfr1 = *(const bf16x8*)&base0[WS2BLK_ + off];
        #pragma unroll
        for (int m=0;m<6;++m){
            bf16x8 afr = *(const bf16x8*)&w2sb[(size_t)(m*16 + lr)*E_ + kk*32 + lk*8];
            acc0[m] = __builtin_amdgcn_mfma_f32_16x16x32_bf16(afr, bfr0, acc0[m], 0, 0, 0);
            acc1[m] = __builtin_amdgcn_mfma_f32_16x16x32_bf16(afr, bfr1, acc1[m], 0, 0, 0);
        }
    }

    const int pos = q*16 + lr;
    const size_t sidx0 = (size_t)s0 + pos;
    #pragma unroll
    for (int m=0;m<6;++m){
        #pragma unroll
        for (int r=0;r<4;++r){
            int c = m*16 + lk*4 + r;
            float bcv = bc[c];
            size_t a0 = ((size_t)(b*C_ + c))*S_ + sidx0;
            out[a0]      = acc0[m][r] + bcv + x[a0];
            out[a0 + 64] = acc1[m][r] + bcv + x[a0 + 64];
        }
    }
}

extern "C" void kernel_launch(void* const* d_in, const int* in_sizes, int n_in,
                              void* d_out, int out_size, void* d_ws, size_t ws_size,
                              hipStream_t stream)
{
    const float* x     = (const float*)d_in[0];
    const float* dwk   = (const float*)d_in[1];
    const float* dwb   = (const float*)d_in[2];
    const float* ln_w  = (const float*)d_in[3];
    const float* ln_b  = (const float*)d_in[4];
    const float* w1    = (const float*)d_in[5];
    const float* b1    = (const float*)d_in[6];
    const float* gamma = (const float*)d_in[7];
    const float* beta  = (const float*)d_in[8];
    const float* w2    = (const float*)d_in[9];
    const float* b2    = (const float*)d_in[10];
    float* out = (float*)d_out;

    char* ws = (char*)d_ws;
    unsigned short* ws1 = (unsigned short*)ws;                        // 28.9 MB used
    unsigned short* ws2 = (unsigned short*)(ws + 57802752);           // 115.6 MB
    unsigned short* w1t = (unsigned short*)(ws + 173408256);          // 73,728 B
    float* sscale = (float*)(ws + 173408256 + 73728);                 // 3,072 B
    float* bc     = sscale + B_*E_;                                   // 384 B
    float* gx2    = bc + C_;                                          // 3,072 B
    // aliased into ws1 region (ws1 dead after k2; written after k2):
    unsigned short* w2s = (unsigned short*)ws;                        // 294,912 B
    // d_out region as scratch (k4 fully overwrites it afterwards):
    float* partial = (float*)d_out;                                   // 3,612,672 B
    unsigned int* pkwg = (unsigned int*)((char*)d_out + 4194304);     // 131,712 B

    kw1t      <<<dim3(144),     256, 0, stream>>>(w1, dwk, w1t, pkwg);
    k1_dwconv <<<dim3(14,96,2), 384, 0, stream>>>(x, pkwg, dwb, ws1);
    k2_ln_pw1 <<<dim3(NBLK_),   256, 0, stream>>>(ws1, ln_w, ln_b, w1t, b1, ws2, partial);
    k3a1      <<<dim3(48,2),    256, 0, stream>>>(partial, gx2);
    k3a2      <<<dim3(2),       384, 0, stream>>>(gx2, gamma, sscale);
    kw2s      <<<dim3(288),     256, 0, stream>>>(w2, sscale, w2s);
    k3c_bc    <<<dim3(96),       64, 0, stream>>>(b2, beta, w2, bc);
    k4_pw2    <<<dim3(N_/128),  256, 0, stream>>>(ws2, w2s, bc, x, out);
}

// Round 18
// 294.775 us; speedup vs baseline: 1.0425x; 1.0425x over previous
//
#include <hip/hip_runtime.h>
#include <hip/hip_fp16.h>
#include <stdint.h>

#define B_ 2
#define C_ 96
#define D_ 24
#define H_ 56
#define W_ 56
#define E_ 384
#define HW_ (H_*W_)        // 3136
#define S_ (D_*HW_)        // 75264
#define N_ (B_*S_)         // 150528
#define NBLK_ 2352         // N_/64 (k2 blocks)
#define WS2BLK_ 24576      // shorts per 64-pos block in fragment-ordered ws2

typedef __attribute__((ext_vector_type(8))) short bf16x8;
typedef __attribute__((ext_vector_type(4))) float f32x4;
typedef __fp16 fp16x2 __attribute__((ext_vector_type(2)));

static __device__ __forceinline__ float bf2f(unsigned short h){
    union { unsigned int u; float f; } v; v.u = ((unsigned int)h) << 16; return v.f;
}
static __device__ __forceinline__ unsigned short f2bf(float x){
    union { float f; unsigned int u; } v; v.f = x;
    unsigned int r = v.u + 0x7FFFu + ((v.u >> 16) & 1u);
    return (unsigned short)(r >> 16);
}
static __device__ __forceinline__ __half2 u2h2(unsigned int u){
    union { unsigned int u; __half2 h; } v; v.u = u; return v.h;
}
static __device__ __forceinline__ unsigned int pk_f16(float a, float b){
    union { fp16x2 h; unsigned int u; } v;
    v.h = __builtin_amdgcn_cvt_pkrtz(a, b);
    return v.u;
}
// fast GELU: v*sigmoid(1.5957691*(v+0.044715 v^3)) via exp2, max |err| ~3e-4
static __device__ __forceinline__ float gelu_f(float v){
    float v2 = v*v;
    float arg = v * fmaf(v2, -0.1029432f, -2.3022080f);
    return v / (1.f + exp2f(arg));
}

// ---------------- K1 (r16-proven): dw conv 8d x 8h x 56w, __hfma2 -> ws1 --------
// halo 14x14x62 staged fp16 (pitch 72, 28.2KB LDS); weights = packed half2(w,w)
// table in GLOBAL, wave-uniform index -> s_load.
__global__ __launch_bounds__(256) void k1_dwconv(
    const float* __restrict__ x, const unsigned int* __restrict__ pkwg,
    const float* __restrict__ bias, unsigned short* __restrict__ ws1)
{
    __shared__ __align__(16) unsigned short hl[14*14*72];
    const int dt = blockIdx.x / 7;   // 0..2
    const int ht = blockIdx.x - dt*7;// 0..6
    const int c  = blockIdx.y, b = blockIdx.z;
    const int d0 = dt*8, h0 = ht*8;
    const int tid = threadIdx.x;
    const float* xc = x + (size_t)(b*C_ + c) * S_;
    const unsigned int* pw = pkwg + c*343;   // block-uniform -> s_load

    for (int i = tid; i < 14*14*31; i += 256){
        int sidx = i / (14*31);
        int rem  = i - sidx*(14*31);
        int hr   = rem / 31;
        int wp   = rem - hr*31;
        int d = d0 - 3 + sidx, h = h0 - 3 + hr, w = wp*2 - 3;
        bool ok = (unsigned)d < D_ && (unsigned)h < H_;
        float v0 = (ok && (unsigned)w     < W_) ? xc[d*HW_ + h*W_ + w]   : 0.f;
        float v1 = (ok && (unsigned)(w+1) < W_) ? xc[d*HW_ + h*W_ + w+1] : 0.f;
        *(unsigned int*)&hl[(sidx*14 + hr)*72 + wp*2] = pk_f16(v0, v1);
    }
    __syncthreads();

    const int wz = tid & 7, hz = (tid >> 3) & 7, dz = tid >> 6;
    if (wz >= 7) return;

    __half2 acc0[4], acc1[4];
    #pragma unroll
    for (int r=0;r<4;++r){ acc0[r] = u2h2(0u); acc1[r] = u2h2(0u); }

    for (int kh = 0; kh < 7; ++kh){
        unsigned int wprev[7];
        for (int si = 0; si < 8; ++si){
            const unsigned short* rp = &hl[((dz*2 + si)*14 + hz + kh)*72 + wz*8];
            uint4 wa = *(const uint4*)rp;
            uint2 wb = *(const uint2*)(rp + 8);
            unsigned int wcq = *(const unsigned int*)(rp + 12);
            unsigned int W[7] = {wa.x, wa.y, wa.z, wa.w, wb.x, wb.y, wcq};
            unsigned int Sh[6];
            #pragma unroll
            for (int m=0;m<6;++m) Sh[m] = __builtin_amdgcn_alignbit(W[m+1], W[m], 16);

            if (si < 7){
                unsigned int wcur[7];
                #pragma unroll
                for (int k=0;k<7;++k) wcur[k] = pw[si*49 + kh*7 + k];
                #pragma unroll
                for (int kw=0; kw<7; ++kw){
                    const int m = kw >> 1;
                    __half2 wp = u2h2(wcur[kw]);
                    #pragma unroll
                    for (int r=0;r<4;++r){
                        __half2 src = (kw & 1) ? u2h2(Sh[m+r]) : u2h2(W[m+r]);
                        acc0[r] = __hfma2(src, wp, acc0[r]);
                    }
                }
                if (si > 0){
                    #pragma unroll
                    for (int kw=0; kw<7; ++kw){
                        const int m = kw >> 1;
                        __half2 wp = u2h2(wprev[kw]);
                        #pragma unroll
                        for (int r=0;r<4;++r){
                            __half2 src = (kw & 1) ? u2h2(Sh[m+r]) : u2h2(W[m+r]);
                            acc1[r] = __hfma2(src, wp, acc1[r]);
                        }
                    }
                }
                #pragma unroll
                for (int k=0;k<7;++k) wprev[k] = wcur[k];
            } else {
                #pragma unroll
                for (int kw=0; kw<7; ++kw){
                    const int m = kw >> 1;
                    __half2 wp = u2h2(wprev[kw]);
                    #pragma unroll
                    for (int r=0;r<4;++r){
                        __half2 src = (kw & 1) ? u2h2(Sh[m+r]) : u2h2(W[m+r]);
                        acc1[r] = __hfma2(src, wp, acc1[r]);
                    }
                }
            }
        }
    }

    const float bs = bias[c];
    float o0v[8], o1v[8];
    #pragma unroll
    for (int r=0;r<4;++r){
        o0v[2*r]   = __low2float(acc0[r])  + bs;
        o0v[2*r+1] = __high2float(acc0[r]) + bs;
        o1v[2*r]   = __low2float(acc1[r])  + bs;
        o1v[2*r+1] = __high2float(acc1[r]) + bs;
    }
    size_t o0 = (size_t)(b*C_ + c)*S_ + (size_t)(d0 + dz*2)*HW_ + (h0 + hz)*W_ + wz*8;
    unsigned int p0 = (unsigned)f2bf(o0v[0]) | ((unsigned)f2bf(o0v[1])<<16);
    unsigned int p1 = (unsigned)f2bf(o0v[2]) | ((unsigned)f2bf(o0v[3])<<16);
    unsigned int p2 = (unsigned)f2bf(o0v[4]) | ((unsigned)f2bf(o0v[5])<<16);
    unsigned int p3 = (unsigned)f2bf(o0v[6]) | ((unsigned)f2bf(o0v[7])<<16);
    *(uint4*)&ws1[o0] = make_uint4(p0,p1,p2,p3);
    p0 = (unsigned)f2bf(o1v[0]) | ((unsigned)f2bf(o1v[1])<<16);
    p1 = (unsigned)f2bf(o1v[2]) | ((unsigned)f2bf(o1v[3])<<16);
    p2 = (unsigned)f2bf(o1v[4]) | ((unsigned)f2bf(o1v[5])<<16);
    p3 = (unsigned)f2bf(o1v[6]) | ((unsigned)f2bf(o1v[7])<<16);
    *(uint4*)&ws1[o0 + HW_] = make_uint4(p0,p1,p2,p3);
}

// ---------- kw1t: w1 transpose to bf16 + dw-weight fp16x2 pack table ------------
__global__ __launch_bounds__(256) void kw1t(
    const float* __restrict__ w1, const float* __restrict__ wk,
    unsigned short* __restrict__ w1t, unsigned int* __restrict__ pkwg)
{
    int idx = blockIdx.x*256 + threadIdx.x;
    if (idx < E_*C_){
        int e = idx / C_, c = idx % C_;
        w1t[idx] = f2bf(w1[c*E_ + e]);
    }
    if (idx < 96*343){
        unsigned short us = __half_as_ushort(__float2half(wk[idx]));
        pkwg[idx] = (unsigned)us | ((unsigned)us << 16);
    }
}

// ------------- K2: LN + pwconv1(MFMA) + GELU -> ws2 (fragment-ordered) ----------
// ws2[blk][q][nt][r][lane]: store instr = 64 lanes x 2B contiguous (128B dense).
__global__ __launch_bounds__(256) void k2_ln_pw1(
    const unsigned short* __restrict__ ws1, const float* __restrict__ ln_w,
    const float* __restrict__ ln_b, const unsigned short* __restrict__ w1t,
    const float* __restrict__ b1, unsigned short* __restrict__ ws2,
    float* __restrict__ partial)
{
    __shared__ unsigned short ly[64*104];
    __shared__ float red1[256], red2[256];
    __shared__ float smu[64], srs[64];
    __shared__ float sq[4][384];
    __shared__ float b1s[384];
    const int tid = threadIdx.x;
    const int p = tid & 63, q = tid >> 6;
    const int n0 = blockIdx.x * 64;
    const int b = n0 / S_;
    const int s0 = n0 - b*S_;
    const size_t basein = (size_t)(b*C_)*S_ + s0 + p;

    for (int i = tid; i < 384; i += 256) b1s[i] = b1[i];

    float v[24];
    float sum=0.f, ssq=0.f;
    #pragma unroll
    for (int i=0;i<24;++i){
        int c = q*24 + i;
        float t = bf2f(ws1[basein + (size_t)c*S_]);
        v[i] = t; sum += t; ssq = fmaf(t,t,ssq);
    }
    red1[tid]=sum; red2[tid]=ssq;
    __syncthreads();
    if (q==0){
        float s1 = red1[p]+red1[64+p]+red1[128+p]+red1[192+p];
        float s2 = red2[p]+red2[64+p]+red2[128+p]+red2[192+p];
        float mu = s1 * (1.f/96.f);
        float var = s2*(1.f/96.f) - mu*mu;
        smu[p]=mu; srs[p]=rsqrtf(var + 1e-6f);
    }
    __syncthreads();
    {
        float mu = smu[p], rs = srs[p];
        #pragma unroll
        for (int i=0;i<24;++i){
            int c = q*24+i;
            ly[p*104 + c] = f2bf((v[i]-mu)*rs*ln_w[c] + ln_b[c]);
        }
    }
    __syncthreads();

    const int lane = tid & 63;
    const int lr = lane & 15;
    const int lk = lane >> 4;
    bf16x8 af[3];
    #pragma unroll
    for (int kk=0;kk<3;++kk)
        af[kk] = *(const bf16x8*)&ly[(q*16 + lr)*104 + kk*32 + lk*8];

    unsigned short* wout = ws2 + (size_t)blockIdx.x*WS2BLK_ + q*6144 + lane;

    for (int nt=0; nt<24; ++nt){
        f32x4 acc = {0.f,0.f,0.f,0.f};
        #pragma unroll
        for (int kk=0;kk<3;++kk){
            bf16x8 bfr = *(const bf16x8*)&w1t[(size_t)(nt*16 + lr)*C_ + kk*32 + lk*8];
            acc = __builtin_amdgcn_mfma_f32_16x16x32_bf16(af[kk], bfr, acc, 0, 0, 0);
        }
        float bias = b1s[nt*16 + lr];
        float ps = 0.f;
        #pragma unroll
        for (int r=0;r<4;++r){
            float val = acc[r] + bias;
            float g = gelu_f(val);
            ps = fmaf(g,g,ps);
            wout[nt*256 + r*64] = f2bf(g);
        }
        ps += __shfl_xor(ps, 16);
        ps += __shfl_xor(ps, 32);
        if (lane < 16) sq[q][nt*16 + lane] = ps;
    }
    __syncthreads();
    // transposed partial: [e][NBLK_]; 2 scattered 4B stores per thread (L2-merged)
    for (int i = tid; i < 384; i += 256)
        partial[(size_t)i*NBLK_ + blockIdx.x] = sq[0][i]+sq[1][i]+sq[2][i]+sq[3][i];
}

// ---------- K3a1: parallel reduce partial[e][NBLK_] -> gx2[b][e] ----------------
// grid (48,2): block handles 8 e-rows; 32 lanes per e, contiguous float4 reads.
__global__ __launch_bounds__(256) void k3a1(
    const float* __restrict__ partial, float* __restrict__ gx2)
{
    const int g = blockIdx.x, b = blockIdx.y;
    const int t = threadIdx.x;
    const int el = t >> 5, lane = t & 31;
    const int e = g*8 + el;
    const float4* row = (const float4*)(partial + (size_t)e*NBLK_ + b*(NBLK_/2));
    float s = 0.f;
    for (int k = lane; k < 294; k += 32){
        float4 v = row[k];
        s += v.x + v.y + v.z + v.w;
    }
    s += __shfl_xor(s, 16);
    s += __shfl_xor(s, 8);
    s += __shfl_xor(s, 4);
    s += __shfl_xor(s, 2);
    s += __shfl_xor(s, 1);
    if (lane == 0) gx2[b*E_ + e] = s;
}

// ---------- K3b (merged k3a2+kw2s+k3c): gx2 -> sscale -> w2s fill, + bc ---------
// blocks 0..287: fill 256 w2s entries each (inline per-block sscale compute);
// block 288: bc[j] = b2[j] + sum_e beta[e]*w2[e,j].
__global__ __launch_bounds__(256) void k3b(
    const float* __restrict__ gx2, const float* __restrict__ gamma,
    const float* __restrict__ w2, const float* __restrict__ beta,
    const float* __restrict__ b2, unsigned short* __restrict__ w2s,
    float* __restrict__ bc)
{
    const int bk = blockIdx.x;
    const int t = threadIdx.x;
    if (bk == 288){
        if (t < 96){
            float a = b2[t];
            for (int e=0;e<E_;++e) a = fmaf(beta[e], w2[e*C_ + t], a);
            bc[t] = a;
        }
        return;
    }
    __shared__ float red[256];
    __shared__ float mean_s;
    const int b = bk / 144;                   // 144*256 = 36864 = C_*E_
    float s = 0.f;
    for (int e = t; e < E_; e += 256)
        s += sqrtf(fmaxf(gx2[b*E_ + e], 0.f));
    red[t] = s;
    __syncthreads();
    if (t < 128) red[t] += red[t+128];
    __syncthreads();
    if (t < 64){
        float v = red[t] + red[t+64];
        v += __shfl_down(v, 32);
        v += __shfl_down(v, 16);
        v += __shfl_down(v, 8);
        v += __shfl_down(v, 4);
        v += __shfl_down(v, 2);
        v += __shfl_down(v, 1);
        if (t == 0) mean_s = v * (1.f/384.f);
    }
    __syncthreads();
    const int idx = bk*256 + t;               // [0, 73728)
    const int rem = idx - b*(C_*E_);
    const int c = rem / E_, e = rem - (rem/E_)*E_;
    float g = sqrtf(fmaxf(gx2[b*E_ + e], 0.f));
    float sc = 1.f + gamma[e] * (g / (mean_s + 1e-6f));
    w2s[idx] = f2bf(w2[e*C_ + c] * sc);
}

// ---------- K4: pwconv2 (MFMA), fragment-ordered ws2 reads ----------------------
__global__ __launch_bounds__(256) void k4_pw2(
    const unsigned short* __restrict__ ws2, const unsigned short* __restrict__ w2s,
    const float* __restrict__ bc, const float* __restrict__ x,
    float* __restrict__ out)
{
    const int tid = threadIdx.x;
    const int n0 = blockIdx.x * 128;
    const int b = n0 / S_;
    const int s0 = n0 - b*S_;
    const int lane = tid & 63, q = tid >> 6;
    const int lr = lane & 15, lk = lane >> 4;

    f32x4 acc0[6], acc1[6];
    #pragma unroll
    for (int m=0;m<6;++m){ acc0[m] = (f32x4){0,0,0,0}; acc1[m] = (f32x4){0,0,0,0}; }
    const unsigned short* w2sb = w2s + (size_t)b*C_*E_;
    // fragment-ordered ws2: lane offset within block
    const unsigned short* base0 = ws2 + (size_t)(blockIdx.x*2)*WS2BLK_
                                + q*6144 + (lr&3)*64 + (lr>>2)*16 + (lk&1)*8;

    for (int kk=0; kk<12; ++kk){
        const int off = (2*kk + (lk>>1))*256;
        bf16x8 bfr0 = *(const bf16x8*)&base0[off];
        bf16x8 bfr1 = *(const bf16x8*)&base0[WS2BLK_ + off];
        #pragma unroll
        for (int m=0;m<6;++m){
            bf16x8 afr = *(const bf16x8*)&w2sb[(size_t)(m*16 + lr)*E_ + kk*32 + lk*8];
            acc0[m] = __builtin_amdgcn_mfma_f32_16x16x32_bf16(afr, bfr0, acc0[m], 0, 0, 0);
            acc1[m] = __builtin_amdgcn_mfma_f32_16x16x32_bf16(afr, bfr1, acc1[m], 0, 0, 0);
        }
    }

    const int pos = q*16 + lr;
    const size_t sidx0 = (size_t)s0 + pos;
    #pragma unroll
    for (int m=0;m<6;++m){
        #pragma unroll
        for (int r=0;r<4;++r){
            int c = m*16 + lk*4 + r;
            float bcv = bc[c];
            size_t a0 = ((size_t)(b*C_ + c))*S_ + sidx0;
            out[a0]      = acc0[m][r] + bcv + x[a0];
            out[a0 + 64] = acc1[m][r] + bcv + x[a0 + 64];
        }
    }
}

extern "C" void kernel_launch(void* const* d_in, const int* in_sizes, int n_in,
                              void* d_out, int out_size, void* d_ws, size_t ws_size,
                              hipStream_t stream)
{
    const float* x     = (const float*)d_in[0];
    const float* dwk   = (const float*)d_in[1];
    const float* dwb   = (const float*)d_in[2];
    const float* ln_w  = (const float*)d_in[3];
    const float* ln_b  = (const float*)d_in[4];
    const float* w1    = (const float*)d_in[5];
    const float* b1    = (const float*)d_in[6];
    const float* gamma = (const float*)d_in[7];
    const float* beta  = (const float*)d_in[8];
    const float* w2    = (const float*)d_in[9];
    const float* b2    = (const float*)d_in[10];
    float* out = (float*)d_out;

    char* ws = (char*)d_ws;
    unsigned short* ws1 = (unsigned short*)ws;                        // 28.9 MB used
    unsigned short* ws2 = (unsigned short*)(ws + 57802752);           // 115.6 MB
    unsigned short* w1t = (unsigned short*)(ws + 173408256);          // 73,728 B
    float* bc     = (float*)(ws + 173408256 + 73728);                 // 384 B
    float* gx2    = bc + C_;                                          // 3,072 B
    // aliased into ws1 region (ws1 dead after k2; written after k2):
    unsigned short* w2s = (unsigned short*)ws;                        // 294,912 B
    // d_out region as scratch (k4 fully overwrites it afterwards):
    float* partial = (float*)d_out;                                   // 3,612,672 B
    unsigned int* pkwg = (unsigned int*)((char*)d_out + 4194304);     // 131,712 B

    kw1t      <<<dim3(144),     256, 0, stream>>>(w1, dwk, w1t, pkwg);
    k1_dwconv <<<dim3(21,96,2), 256, 0, stream>>>(x, pkwg, dwb, ws1);
    k2_ln_pw1 <<<dim3(NBLK_),   256, 0, stream>>>(ws1, ln_w, ln_b, w1t, b1, ws2, partial);
    k3a1      <<<dim3(48,2),    256, 0, stream>>>(partial, gx2);
    k3b       <<<dim3(289),     256, 0, stream>>>(gx2, gamma, w2, beta, b2, w2s, bc);
    k4_pw2    <<<dim3(N_/128),  256, 0, stream>>>(ws2, w2s, bc, x, out);
}

// Round 19
// 285.488 us; speedup vs baseline: 1.0764x; 1.0325x over previous
//
#include <hip/hip_runtime.h>
#include <hip/hip_fp16.h>
#include <stdint.h>

#define B_ 2
#define C_ 96
#define D_ 24
#define H_ 56
#define W_ 56
#define E_ 384
#define HW_ (H_*W_)        // 3136
#define S_ (D_*HW_)        // 75264
#define N_ (B_*S_)         // 150528
#define NBLK_ 2352         // N_/64 (k2 blocks)
#define WS2BLK_ 24576      // BYTES per 64-pos block in fragment-ordered fp8 ws2

typedef __attribute__((ext_vector_type(8))) short bf16x8;
typedef __attribute__((ext_vector_type(4))) float f32x4;
typedef __fp16 fp16x2 __attribute__((ext_vector_type(2)));

static __device__ __forceinline__ float bf2f(unsigned short h){
    union { unsigned int u; float f; } v; v.u = ((unsigned int)h) << 16; return v.f;
}
static __device__ __forceinline__ unsigned short f2bf(float x){
    union { float f; unsigned int u; } v; v.f = x;
    unsigned int r = v.u + 0x7FFFu + ((v.u >> 16) & 1u);
    return (unsigned short)(r >> 16);
}
static __device__ __forceinline__ __half2 u2h2(unsigned int u){
    union { unsigned int u; __half2 h; } v; v.u = u; return v.h;
}
static __device__ __forceinline__ unsigned int pk_f16(float a, float b){
    union { fp16x2 h; unsigned int u; } v;
    v.h = __builtin_amdgcn_cvt_pkrtz(a, b);
    return v.u;
}
// fast GELU: v*sigmoid(1.5957691*(v+0.044715 v^3)) via exp2, max |err| ~3e-4
static __device__ __forceinline__ float gelu_f(float v){
    float v2 = v*v;
    float arg = v * fmaf(v2, -0.1029432f, -2.3022080f);
    return v / (1.f + exp2f(arg));
}

// ---------------- K1 (r16-proven): dw conv 8d x 8h x 56w, __hfma2 -> ws1 --------
__global__ __launch_bounds__(256) void k1_dwconv(
    const float* __restrict__ x, const unsigned int* __restrict__ pkwg,
    const float* __restrict__ bias, unsigned short* __restrict__ ws1)
{
    __shared__ __align__(16) unsigned short hl[14*14*72];
    const int dt = blockIdx.x / 7;   // 0..2
    const int ht = blockIdx.x - dt*7;// 0..6
    const int c  = blockIdx.y, b = blockIdx.z;
    const int d0 = dt*8, h0 = ht*8;
    const int tid = threadIdx.x;
    const float* xc = x + (size_t)(b*C_ + c) * S_;
    const unsigned int* pw = pkwg + c*343;   // block-uniform -> s_load

    for (int i = tid; i < 14*14*31; i += 256){
        int sidx = i / (14*31);
        int rem  = i - sidx*(14*31);
        int hr   = rem / 31;
        int wp   = rem - hr*31;
        int d = d0 - 3 + sidx, h = h0 - 3 + hr, w = wp*2 - 3;
        bool ok = (unsigned)d < D_ && (unsigned)h < H_;
        float v0 = (ok && (unsigned)w     < W_) ? xc[d*HW_ + h*W_ + w]   : 0.f;
        float v1 = (ok && (unsigned)(w+1) < W_) ? xc[d*HW_ + h*W_ + w+1] : 0.f;
        *(unsigned int*)&hl[(sidx*14 + hr)*72 + wp*2] = pk_f16(v0, v1);
    }
    __syncthreads();

    const int wz = tid & 7, hz = (tid >> 3) & 7, dz = tid >> 6;
    if (wz >= 7) return;

    __half2 acc0[4], acc1[4];
    #pragma unroll
    for (int r=0;r<4;++r){ acc0[r] = u2h2(0u); acc1[r] = u2h2(0u); }

    for (int kh = 0; kh < 7; ++kh){
        unsigned int wprev[7];
        for (int si = 0; si < 8; ++si){
            const unsigned short* rp = &hl[((dz*2 + si)*14 + hz + kh)*72 + wz*8];
            uint4 wa = *(const uint4*)rp;
            uint2 wb = *(const uint2*)(rp + 8);
            unsigned int wcq = *(const unsigned int*)(rp + 12);
            unsigned int W[7] = {wa.x, wa.y, wa.z, wa.w, wb.x, wb.y, wcq};
            unsigned int Sh[6];
            #pragma unroll
            for (int m=0;m<6;++m) Sh[m] = __builtin_amdgcn_alignbit(W[m+1], W[m], 16);

            if (si < 7){
                unsigned int wcur[7];
                #pragma unroll
                for (int k=0;k<7;++k) wcur[k] = pw[si*49 + kh*7 + k];
                #pragma unroll
                for (int kw=0; kw<7; ++kw){
                    const int m = kw >> 1;
                    __half2 wp = u2h2(wcur[kw]);
                    #pragma unroll
                    for (int r=0;r<4;++r){
                        __half2 src = (kw & 1) ? u2h2(Sh[m+r]) : u2h2(W[m+r]);
                        acc0[r] = __hfma2(src, wp, acc0[r]);
                    }
                }
                if (si > 0){
                    #pragma unroll
                    for (int kw=0; kw<7; ++kw){
                        const int m = kw >> 1;
                        __half2 wp = u2h2(wprev[kw]);
                        #pragma unroll
                        for (int r=0;r<4;++r){
                            __half2 src = (kw & 1) ? u2h2(Sh[m+r]) : u2h2(W[m+r]);
                            acc1[r] = __hfma2(src, wp, acc1[r]);
                        }
                    }
                }
                #pragma unroll
                for (int k=0;k<7;++k) wprev[k] = wcur[k];
            } else {
                #pragma unroll
                for (int kw=0; kw<7; ++kw){
                    const int m = kw >> 1;
                    __half2 wp = u2h2(wprev[kw]);
                    #pragma unroll
                    for (int r=0;r<4;++r){
                        __half2 src = (kw & 1) ? u2h2(Sh[m+r]) : u2h2(W[m+r]);
                        acc1[r] = __hfma2(src, wp, acc1[r]);
                    }
                }
            }
        }
    }

    const float bs = bias[c];
    float o0v[8], o1v[8];
    #pragma unroll
    for (int r=0;r<4;++r){
        o0v[2*r]   = __low2float(acc0[r])  + bs;
        o0v[2*r+1] = __high2float(acc0[r]) + bs;
        o1v[2*r]   = __low2float(acc1[r])  + bs;
        o1v[2*r+1] = __high2float(acc1[r]) + bs;
    }
    size_t o0 = (size_t)(b*C_ + c)*S_ + (size_t)(d0 + dz*2)*HW_ + (h0 + hz)*W_ + wz*8;
    unsigned int p0 = (unsigned)f2bf(o0v[0]) | ((unsigned)f2bf(o0v[1])<<16);
    unsigned int p1 = (unsigned)f2bf(o0v[2]) | ((unsigned)f2bf(o0v[3])<<16);
    unsigned int p2 = (unsigned)f2bf(o0v[4]) | ((unsigned)f2bf(o0v[5])<<16);
    unsigned int p3 = (unsigned)f2bf(o0v[6]) | ((unsigned)f2bf(o0v[7])<<16);
    *(uint4*)&ws1[o0] = make_uint4(p0,p1,p2,p3);
    p0 = (unsigned)f2bf(o1v[0]) | ((unsigned)f2bf(o1v[1])<<16);
    p1 = (unsigned)f2bf(o1v[2]) | ((unsigned)f2bf(o1v[3])<<16);
    p2 = (unsigned)f2bf(o1v[4]) | ((unsigned)f2bf(o1v[5])<<16);
    p3 = (unsigned)f2bf(o1v[6]) | ((unsigned)f2bf(o1v[7])<<16);
    *(uint4*)&ws1[o0 + HW_] = make_uint4(p0,p1,p2,p3);
}

// ---------- kw1t: w1 transpose to bf16 + dw-weight fp16x2 pack table ------------
__global__ __launch_bounds__(256) void kw1t(
    const float* __restrict__ w1, const float* __restrict__ wk,
    unsigned short* __restrict__ w1t, unsigned int* __restrict__ pkwg)
{
    int idx = blockIdx.x*256 + threadIdx.x;
    if (idx < E_*C_){
        int e = idx / C_, c = idx % C_;
        w1t[idx] = f2bf(w1[c*E_ + e]);
    }
    if (idx < 96*343){
        unsigned short us = __half_as_ushort(__float2half(wk[idx]));
        pkwg[idx] = (unsigned)us | ((unsigned)us << 16);
    }
}

// ------------- K2: LN + pwconv1(MFMA) + GELU -> ws2 (fragment-ordered fp8) ------
// ws2[blk][q][nt][r][lane] bytes: store = 64 lanes x 1B contiguous (64B dense).
__global__ __launch_bounds__(256) void k2_ln_pw1(
    const unsigned short* __restrict__ ws1, const float* __restrict__ ln_w,
    const float* __restrict__ ln_b, const unsigned short* __restrict__ w1t,
    const float* __restrict__ b1, unsigned char* __restrict__ ws2,
    float* __restrict__ partial)
{
    __shared__ unsigned short ly[64*104];
    __shared__ float red1[256], red2[256];
    __shared__ float smu[64], srs[64];
    __shared__ float sq[4][384];
    __shared__ float b1s[384];
    const int tid = threadIdx.x;
    const int p = tid & 63, q = tid >> 6;
    const int n0 = blockIdx.x * 64;
    const int b = n0 / S_;
    const int s0 = n0 - b*S_;
    const size_t basein = (size_t)(b*C_)*S_ + s0 + p;

    for (int i = tid; i < 384; i += 256) b1s[i] = b1[i];

    float v[24];
    float sum=0.f, ssq=0.f;
    #pragma unroll
    for (int i=0;i<24;++i){
        int c = q*24 + i;
        float t = bf2f(ws1[basein + (size_t)c*S_]);
        v[i] = t; sum += t; ssq = fmaf(t,t,ssq);
    }
    red1[tid]=sum; red2[tid]=ssq;
    __syncthreads();
    if (q==0){
        float s1 = red1[p]+red1[64+p]+red1[128+p]+red1[192+p];
        float s2 = red2[p]+red2[64+p]+red2[128+p]+red2[192+p];
        float mu = s1 * (1.f/96.f);
        float var = s2*(1.f/96.f) - mu*mu;
        smu[p]=mu; srs[p]=rsqrtf(var + 1e-6f);
    }
    __syncthreads();
    {
        float mu = smu[p], rs = srs[p];
        #pragma unroll
        for (int i=0;i<24;++i){
            int c = q*24+i;
            ly[p*104 + c] = f2bf((v[i]-mu)*rs*ln_w[c] + ln_b[c]);
        }
    }
    __syncthreads();

    const int lane = tid & 63;
    const int lr = lane & 15;
    const int lk = lane >> 4;
    bf16x8 af[3];
    #pragma unroll
    for (int kk=0;kk<3;++kk)
        af[kk] = *(const bf16x8*)&ly[(q*16 + lr)*104 + kk*32 + lk*8];

    unsigned char* wout = ws2 + (size_t)blockIdx.x*WS2BLK_ + q*6144 + lane;

    for (int nt=0; nt<24; ++nt){
        f32x4 acc = {0.f,0.f,0.f,0.f};
        #pragma unroll
        for (int kk=0;kk<3;++kk){
            bf16x8 bfr = *(const bf16x8*)&w1t[(size_t)(nt*16 + lr)*C_ + kk*32 + lk*8];
            acc = __builtin_amdgcn_mfma_f32_16x16x32_bf16(af[kk], bfr, acc, 0, 0, 0);
        }
        float bias = b1s[nt*16 + lr];
        float gv[4];
        float ps = 0.f;
        #pragma unroll
        for (int r=0;r<4;++r){
            float val = acc[r] + bias;
            float g = gelu_f(val);
            gv[r] = g;
            ps = fmaf(g,g,ps);
        }
        int pk = __builtin_amdgcn_cvt_pk_fp8_f32(gv[0], gv[1], 0, false);
        pk     = __builtin_amdgcn_cvt_pk_fp8_f32(gv[2], gv[3], pk, true);
        unsigned char* wb = wout + nt*256;
        wb[0]   = (unsigned char)( pk        & 0xff);
        wb[64]  = (unsigned char)((pk >> 8)  & 0xff);
        wb[128] = (unsigned char)((pk >> 16) & 0xff);
        wb[192] = (unsigned char)((pk >> 24) & 0xff);
        ps += __shfl_xor(ps, 16);
        ps += __shfl_xor(ps, 32);
        if (lane < 16) sq[q][nt*16 + lane] = ps;
    }
    __syncthreads();
    // transposed partial: [e][NBLK_]; 2 scattered 4B stores per thread (L2-merged)
    for (int i = tid; i < 384; i += 256)
        partial[(size_t)i*NBLK_ + blockIdx.x] = sq[0][i]+sq[1][i]+sq[2][i]+sq[3][i];
}

// ---------- K3a1: parallel reduce partial[e][NBLK_] -> gx2[b][e] ----------------
__global__ __launch_bounds__(256) void k3a1(
    const float* __restrict__ partial, float* __restrict__ gx2)
{
    const int g = blockIdx.x, b = blockIdx.y;
    const int t = threadIdx.x;
    const int el = t >> 5, lane = t & 31;
    const int e = g*8 + el;
    const float4* row = (const float4*)(partial + (size_t)e*NBLK_ + b*(NBLK_/2));
    float s = 0.f;
    for (int k = lane; k < 294; k += 32){
        float4 v = row[k];
        s += v.x + v.y + v.z + v.w;
    }
    s += __shfl_xor(s, 16);
    s += __shfl_xor(s, 8);
    s += __shfl_xor(s, 4);
    s += __shfl_xor(s, 2);
    s += __shfl_xor(s, 1);
    if (lane == 0) gx2[b*E_ + e] = s;
}

// ---------- K3b: gx2 -> sscale -> w2s fill (fp8), + bc --------------------------
__global__ __launch_bounds__(256) void k3b(
    const float* __restrict__ gx2, const float* __restrict__ gamma,
    const float* __restrict__ w2, const float* __restrict__ beta,
    const float* __restrict__ b2, unsigned char* __restrict__ w2s,
    float* __restrict__ bc)
{
    const int bk = blockIdx.x;
    const int t = threadIdx.x;
    if (bk == 288){
        if (t < 96){
            float a = b2[t];
            for (int e=0;e<E_;++e) a = fmaf(beta[e], w2[e*C_ + t], a);
            bc[t] = a;
        }
        return;
    }
    __shared__ float red[256];
    __shared__ float mean_s;
    const int b = bk / 144;                   // 144*256 = 36864 = C_*E_
    float s = 0.f;
    for (int e = t; e < E_; e += 256)
        s += sqrtf(fmaxf(gx2[b*E_ + e], 0.f));
    red[t] = s;
    __syncthreads();
    if (t < 128) red[t] += red[t+128];
    __syncthreads();
    if (t < 64){
        float v = red[t] + red[t+64];
        v += __shfl_down(v, 32);
        v += __shfl_down(v, 16);
        v += __shfl_down(v, 8);
        v += __shfl_down(v, 4);
        v += __shfl_down(v, 2);
        v += __shfl_down(v, 1);
        if (t == 0) mean_s = v * (1.f/384.f);
    }
    __syncthreads();
    const int idx = bk*256 + t;               // [0, 73728)
    const int rem = idx - b*(C_*E_);
    const int c = rem / E_, e = rem - (rem/E_)*E_;
    float g = sqrtf(fmaxf(gx2[b*E_ + e], 0.f));
    float sc = 1.f + gamma[e] * (g / (mean_s + 1e-6f));
    float val = w2[e*C_ + c] * sc;
    int pk = __builtin_amdgcn_cvt_pk_fp8_f32(val, val, 0, false);
    w2s[idx] = (unsigned char)(pk & 0xff);
}

// ---------- K4: pwconv2 (fp8 MFMA), fragment-ordered fp8 ws2 reads --------------
__global__ __launch_bounds__(256) void k4_pw2(
    const unsigned char* __restrict__ ws2, const unsigned char* __restrict__ w2s,
    const float* __restrict__ bc, const float* __restrict__ x,
    float* __restrict__ out)
{
    const int tid = threadIdx.x;
    const int n0 = blockIdx.x * 128;
    const int b = n0 / S_;
    const int s0 = n0 - b*S_;
    const int lane = tid & 63, q = tid >> 6;
    const int lr = lane & 15, lk = lane >> 4;

    f32x4 acc0[6], acc1[6];
    #pragma unroll
    for (int m=0;m<6;++m){ acc0[m] = (f32x4){0,0,0,0}; acc1[m] = (f32x4){0,0,0,0}; }
    const unsigned char* w2sb = w2s + (size_t)b*C_*E_;
    const unsigned char* base0 = ws2 + (size_t)(blockIdx.x*2)*WS2BLK_
                               + q*6144 + (lr&3)*64 + (lr>>2)*16 + (lk&1)*8;

    for (int kk=0; kk<12; ++kk){
        const int off = (2*kk + (lk>>1))*256;
        long bfr0 = *(const long*)&base0[off];
        long bfr1 = *(const long*)&base0[WS2BLK_ + off];
        #pragma unroll
        for (int m=0;m<6;++m){
            long afr = *(const long*)&w2sb[(size_t)(m*16 + lr)*E_ + kk*32 + lk*8];
            acc0[m] = __builtin_amdgcn_mfma_f32_16x16x32_fp8_fp8(afr, bfr0, acc0[m], 0, 0, 0);
            acc1[m] = __builtin_amdgcn_mfma_f32_16x16x32_fp8_fp8(afr, bfr1, acc1[m], 0, 0, 0);
        }
    }

    const int pos = q*16 + lr;
    const size_t sidx0 = (size_t)s0 + pos;
    #pragma unroll
    for (int m=0;m<6;++m){
        #pragma unroll
        for (int r=0;r<4;++r){
            int c = m*16 + lk*4 + r;
            float bcv = bc[c];
            size_t a0 = ((size_t)(b*C_ + c))*S_ + sidx0;
            out[a0]      = acc0[m][r] + bcv + x[a0];
            out[a0 + 64] = acc1[m][r] + bcv + x[a0 + 64];
        }
    }
}

extern "C" void kernel_launch(void* const* d_in, const int* in_sizes, int n_in,
                              void* d_out, int out_size, void* d_ws, size_t ws_size,
                              hipStream_t stream)
{
    const float* x     = (const float*)d_in[0];
    const float* dwk   = (const float*)d_in[1];
    const float* dwb   = (const float*)d_in[2];
    const float* ln_w  = (const float*)d_in[3];
    const float* ln_b  = (const float*)d_in[4];
    const float* w1    = (const float*)d_in[5];
    const float* b1    = (const float*)d_in[6];
    const float* gamma = (const float*)d_in[7];
    const float* beta  = (const float*)d_in[8];
    const float* w2    = (const float*)d_in[9];
    const float* b2    = (const float*)d_in[10];
    float* out = (float*)d_out;

    char* ws = (char*)d_ws;
    unsigned short* ws1 = (unsigned short*)ws;                        // 28.9 MB used
    unsigned char*  ws2 = (unsigned char*)(ws + 57802752);            // 57.8 MB (fp8)
    unsigned short* w1t = (unsigned short*)(ws + 173408256);          // 73,728 B
    float* bc     = (float*)(ws + 173408256 + 73728);                 // 384 B
    float* gx2    = bc + C_;                                          // 3,072 B
    // aliased into ws1 region (ws1 dead after k2; written after k2):
    unsigned char* w2s = (unsigned char*)ws;                          // 73,728 B (fp8)
    // d_out region as scratch (k4 fully overwrites it afterwards):
    float* partial = (float*)d_out;                                   // 3,612,672 B
    unsigned int* pkwg = (unsigned int*)((char*)d_out + 4194304);     // 131,712 B

    kw1t      <<<dim3(144),     256, 0, stream>>>(w1, dwk, w1t, pkwg);
    k1_dwconv <<<dim3(21,96,2), 256, 0, stream>>>(x, pkwg, dwb, ws1);
    k2_ln_pw1 <<<dim3(NBLK_),   256, 0, stream>>>(ws1, ln_w, ln_b, w1t, b1, ws2, partial);
    k3a1      <<<dim3(48,2),    256, 0, stream>>>(partial, gx2);
    k3b       <<<dim3(289),     256, 0, stream>>>(gx2, gamma, w2, beta, b2, w2s, bc);
    k4_pw2    <<<dim3(N_/128),  256, 0, stream>>>(ws2, w2s, bc, x, out);
}

// Round 20
// 282.207 us; speedup vs baseline: 1.0889x; 1.0116x over previous
//
#include <hip/hip_runtime.h>
#include <hip/hip_fp16.h>
#include <stdint.h>

#define B_ 2
#define C_ 96
#define D_ 24
#define H_ 56
#define W_ 56
#define E_ 384
#define HW_ (H_*W_)        // 3136
#define S_ (D_*HW_)        // 75264
#define N_ (B_*S_)         // 150528
#define NBLK_ 2352         // N_/64 (k2 blocks)
#define WS2BLK_ 24576      // BYTES per 64-pos block in fragment-ordered fp8 ws2

typedef __attribute__((ext_vector_type(8))) short bf16x8;
typedef __attribute__((ext_vector_type(4))) float f32x4;
typedef __fp16 fp16x2 __attribute__((ext_vector_type(2)));

static __device__ __forceinline__ float bf2f(unsigned short h){
    union { unsigned int u; float f; } v; v.u = ((unsigned int)h) << 16; return v.f;
}
static __device__ __forceinline__ unsigned short f2bf(float x){
    union { float f; unsigned int u; } v; v.f = x;
    unsigned int r = v.u + 0x7FFFu + ((v.u >> 16) & 1u);
    return (unsigned short)(r >> 16);
}
static __device__ __forceinline__ fp16x2 u2f16(unsigned int u){
    union { unsigned int u; fp16x2 h; } v; v.u = u; return v.h;
}
static __device__ __forceinline__ unsigned int pk_f16(float a, float b){
    union { fp16x2 h; unsigned int u; } v;
    v.h = __builtin_amdgcn_cvt_pkrtz(a, b);
    return v.u;
}
// fast GELU: v*sigmoid(1.5957691*(v+0.044715 v^3)) via exp2, max |err| ~3e-4
static __device__ __forceinline__ float gelu_f(float v){
    float v2 = v*v;
    float arg = v * fmaf(v2, -0.1029432f, -2.3022080f);
    return v / (1.f + exp2f(arg));
}

// ---------------- K1: dw conv 8d x 8h x 56w, fp16x2 elementwise-fma -> ws1 ------
// halo 14x14x62 staged fp16 (pitch 72, 28.2KB LDS); weights = packed half2(w,w)
// table in GLOBAL, wave-uniform index -> s_load.
__global__ __launch_bounds__(256) void k1_dwconv(
    const float* __restrict__ x, const unsigned int* __restrict__ pkwg,
    const float* __restrict__ bias, unsigned short* __restrict__ ws1)
{
    __shared__ __align__(16) unsigned short hl[14*14*72];
    const int dt = blockIdx.x / 7;   // 0..2
    const int ht = blockIdx.x - dt*7;// 0..6
    const int c  = blockIdx.y, b = blockIdx.z;
    const int d0 = dt*8, h0 = ht*8;
    const int tid = threadIdx.x;
    const float* xc = x + (size_t)(b*C_ + c) * S_;
    const unsigned int* pw = pkwg + c*343;   // block-uniform -> s_load

    for (int i = tid; i < 14*14*31; i += 256){
        int sidx = i / (14*31);
        int rem  = i - sidx*(14*31);
        int hr   = rem / 31;
        int wp   = rem - hr*31;
        int d = d0 - 3 + sidx, h = h0 - 3 + hr, w = wp*2 - 3;
        bool ok = (unsigned)d < D_ && (unsigned)h < H_;
        float v0 = (ok && (unsigned)w     < W_) ? xc[d*HW_ + h*W_ + w]   : 0.f;
        float v1 = (ok && (unsigned)(w+1) < W_) ? xc[d*HW_ + h*W_ + w+1] : 0.f;
        *(unsigned int*)&hl[(sidx*14 + hr)*72 + wp*2] = pk_f16(v0, v1);
    }
    __syncthreads();

    const int wz = tid & 7, hz = (tid >> 3) & 7, dz = tid >> 6;
    if (wz >= 7) return;

    fp16x2 acc0[4], acc1[4];
    #pragma unroll
    for (int r=0;r<4;++r){ acc0[r] = u2f16(0u); acc1[r] = u2f16(0u); }

    for (int kh = 0; kh < 7; ++kh){
        unsigned int wprev[7];
        for (int si = 0; si < 8; ++si){
            const unsigned short* rp = &hl[((dz*2 + si)*14 + hz + kh)*72 + wz*8];
            uint4 wa = *(const uint4*)rp;
            uint2 wb = *(const uint2*)(rp + 8);
            unsigned int wcq = *(const unsigned int*)(rp + 12);
            unsigned int W[7] = {wa.x, wa.y, wa.z, wa.w, wb.x, wb.y, wcq};
            unsigned int Sh[6];
            #pragma unroll
            for (int m=0;m<6;++m) Sh[m] = __builtin_amdgcn_alignbit(W[m+1], W[m], 16);

            if (si < 7){
                unsigned int wcur[7];
                #pragma unroll
                for (int k=0;k<7;++k) wcur[k] = pw[si*49 + kh*7 + k];
                #pragma unroll
                for (int kw=0; kw<7; ++kw){
                    const int m = kw >> 1;
                    fp16x2 wp = u2f16(wcur[kw]);
                    #pragma unroll
                    for (int r=0;r<4;++r){
                        fp16x2 src = (kw & 1) ? u2f16(Sh[m+r]) : u2f16(W[m+r]);
                        acc0[r] = __builtin_elementwise_fma(src, wp, acc0[r]);
                    }
                }
                if (si > 0){
                    #pragma unroll
                    for (int kw=0; kw<7; ++kw){
                        const int m = kw >> 1;
                        fp16x2 wp = u2f16(wprev[kw]);
                        #pragma unroll
                        for (int r=0;r<4;++r){
                            fp16x2 src = (kw & 1) ? u2f16(Sh[m+r]) : u2f16(W[m+r]);
                            acc1[r] = __builtin_elementwise_fma(src, wp, acc1[r]);
                        }
                    }
                }
                #pragma unroll
                for (int k=0;k<7;++k) wprev[k] = wcur[k];
            } else {
                #pragma unroll
                for (int kw=0; kw<7; ++kw){
                    const int m = kw >> 1;
                    fp16x2 wp = u2f16(wprev[kw]);
                    #pragma unroll
                    for (int r=0;r<4;++r){
                        fp16x2 src = (kw & 1) ? u2f16(Sh[m+r]) : u2f16(W[m+r]);
                        acc1[r] = __builtin_elementwise_fma(src, wp, acc1[r]);
                    }
                }
            }
        }
    }

    const float bs = bias[c];
    float o0v[8], o1v[8];
    #pragma unroll
    for (int r=0;r<4;++r){
        o0v[2*r]   = (float)acc0[r][0] + bs;
        o0v[2*r+1] = (float)acc0[r][1] + bs;
        o1v[2*r]   = (float)acc1[r][0] + bs;
        o1v[2*r+1] = (float)acc1[r][1] + bs;
    }
    size_t o0 = (size_t)(b*C_ + c)*S_ + (size_t)(d0 + dz*2)*HW_ + (h0 + hz)*W_ + wz*8;
    unsigned int p0 = (unsigned)f2bf(o0v[0]) | ((unsigned)f2bf(o0v[1])<<16);
    unsigned int p1 = (unsigned)f2bf(o0v[2]) | ((unsigned)f2bf(o0v[3])<<16);
    unsigned int p2 = (unsigned)f2bf(o0v[4]) | ((unsigned)f2bf(o0v[5])<<16);
    unsigned int p3 = (unsigned)f2bf(o0v[6]) | ((unsigned)f2bf(o0v[7])<<16);
    *(uint4*)&ws1[o0] = make_uint4(p0,p1,p2,p3);
    p0 = (unsigned)f2bf(o1v[0]) | ((unsigned)f2bf(o1v[1])<<16);
    p1 = (unsigned)f2bf(o1v[2]) | ((unsigned)f2bf(o1v[3])<<16);
    p2 = (unsigned)f2bf(o1v[4]) | ((unsigned)f2bf(o1v[5])<<16);
    p3 = (unsigned)f2bf(o1v[6]) | ((unsigned)f2bf(o1v[7])<<16);
    *(uint4*)&ws1[o0 + HW_] = make_uint4(p0,p1,p2,p3);
}

// ---------- kw1t: w1t[e][c] = bf16(ln_w[c]*w1[c,e]); pkwg; A,B vectors ----------
__global__ __launch_bounds__(256) void kw1t(
    const float* __restrict__ w1, const float* __restrict__ wk,
    const float* __restrict__ ln_w, const float* __restrict__ ln_b,
    const float* __restrict__ b1, unsigned short* __restrict__ w1t,
    unsigned int* __restrict__ pkwg, float* __restrict__ Av, float* __restrict__ Bv)
{
    int bk = blockIdx.x;
    if (bk >= 144){
        int e = (bk - 144)*256 + threadIdx.x;
        if (e < E_){
            float a = 0.f, bb = b1[e];
            for (int c=0;c<C_;++c){
                float w = w1[c*E_ + e];
                a  = fmaf(ln_w[c], w, a);
                bb = fmaf(ln_b[c], w, bb);
            }
            Av[e] = a; Bv[e] = bb;
        }
        return;
    }
    int idx = bk*256 + threadIdx.x;
    if (idx < E_*C_){
        int e = idx / C_, c = idx % C_;
        w1t[idx] = f2bf(w1[c*E_ + e] * ln_w[c]);
    }
    if (idx < 96*343){
        unsigned short us = __half_as_ushort(__float2half(wk[idx]));
        pkwg[idx] = (unsigned)us | ((unsigned)us << 16);
    }
}

// ------------- K2: LN-folded pwconv1(MFMA) + GELU -> ws2 (fp8, frag-ordered) ----
// z = rs*(y@w1g) - rs*mu*A + B; raw-y MFMA, affine fix in epilogue.
__global__ __launch_bounds__(256) void k2_ln_pw1(
    const unsigned short* __restrict__ ws1, const unsigned short* __restrict__ w1t,
    const float* __restrict__ Av, const float* __restrict__ Bv,
    unsigned char* __restrict__ ws2, float* __restrict__ partial)
{
    __shared__ unsigned short ly[64*104];
    __shared__ float red1[256], red2[256];
    __shared__ float smu[64], srs[64];
    __shared__ float sq[4][384];
    __shared__ float As[384], Bs[384];
    const int tid = threadIdx.x;
    const int p = tid & 63, q = tid >> 6;
    const int n0 = blockIdx.x * 64;
    const int b = n0 / S_;
    const int s0 = n0 - b*S_;
    const size_t basein = (size_t)(b*C_)*S_ + s0 + p;

    for (int i = tid; i < 384; i += 256){ As[i] = Av[i]; Bs[i] = Bv[i]; }

    float sum=0.f, ssq=0.f;
    #pragma unroll
    for (int i=0;i<24;++i){
        int c = q*24 + i;
        unsigned short u = ws1[basein + (size_t)c*S_];
        float t = bf2f(u);
        ly[p*104 + c] = u;
        sum += t; ssq = fmaf(t,t,ssq);
    }
    red1[tid]=sum; red2[tid]=ssq;
    __syncthreads();
    if (q==0){
        float s1 = red1[p]+red1[64+p]+red1[128+p]+red1[192+p];
        float s2 = red2[p]+red2[64+p]+red2[128+p]+red2[192+p];
        float mu = s1 * (1.f/96.f);
        float var = s2*(1.f/96.f) - mu*mu;
        smu[p]=mu; srs[p]=rsqrtf(var + 1e-6f);
    }
    __syncthreads();

    const int lane = tid & 63;
    const int lr = lane & 15;
    const int lk = lane >> 4;
    bf16x8 af[3];
    #pragma unroll
    for (int kk=0;kk<3;++kk)
        af[kk] = *(const bf16x8*)&ly[(q*16 + lr)*104 + kk*32 + lk*8];

    float rsv[4], rmv[4];
    #pragma unroll
    for (int r=0;r<4;++r){
        int pos = q*16 + lk*4 + r;
        rsv[r] = srs[pos];
        rmv[r] = -rsv[r]*smu[pos];
    }

    unsigned char* wout = ws2 + (size_t)blockIdx.x*WS2BLK_ + q*6144 + lane;

    for (int nt=0; nt<24; ++nt){
        f32x4 acc = {0.f,0.f,0.f,0.f};
        #pragma unroll
        for (int kk=0;kk<3;++kk){
            bf16x8 bfr = *(const bf16x8*)&w1t[(size_t)(nt*16 + lr)*C_ + kk*32 + lk*8];
            acc = __builtin_amdgcn_mfma_f32_16x16x32_bf16(af[kk], bfr, acc, 0, 0, 0);
        }
        float Ae = As[nt*16 + lr];
        float Be = Bs[nt*16 + lr];
        float gv[4];
        float ps = 0.f;
        #pragma unroll
        for (int r=0;r<4;++r){
            float val = fmaf(rsv[r], acc[r], fmaf(rmv[r], Ae, Be));
            float g = gelu_f(val);
            gv[r] = g;
            ps = fmaf(g,g,ps);
        }
        int pk = __builtin_amdgcn_cvt_pk_fp8_f32(gv[0], gv[1], 0, false);
        pk     = __builtin_amdgcn_cvt_pk_fp8_f32(gv[2], gv[3], pk, true);
        unsigned char* wb = wout + nt*256;
        wb[0]   = (unsigned char)( pk        & 0xff);
        wb[64]  = (unsigned char)((pk >> 8)  & 0xff);
        wb[128] = (unsigned char)((pk >> 16) & 0xff);
        wb[192] = (unsigned char)((pk >> 24) & 0xff);
        ps += __shfl_xor(ps, 16);
        ps += __shfl_xor(ps, 32);
        if (lane < 16) sq[q][nt*16 + lane] = ps;
    }
    __syncthreads();
    for (int i = tid; i < 384; i += 256)
        partial[(size_t)i*NBLK_ + blockIdx.x] = sq[0][i]+sq[1][i]+sq[2][i]+sq[3][i];
}

// ---------- K3a1: parallel reduce partial[e][NBLK_] -> gx2[b][e] ----------------
__global__ __launch_bounds__(256) void k3a1(
    const float* __restrict__ partial, float* __restrict__ gx2)
{
    const int g = blockIdx.x, b = blockIdx.y;
    const int t = threadIdx.x;
    const int el = t >> 5, lane = t & 31;
    const int e = g*8 + el;
    const float4* row = (const float4*)(partial + (size_t)e*NBLK_ + b*(NBLK_/2));
    float s = 0.f;
    for (int k = lane; k < 294; k += 32){
        float4 v = row[k];
        s += v.x + v.y + v.z + v.w;
    }
    s += __shfl_xor(s, 16);
    s += __shfl_xor(s, 8);
    s += __shfl_xor(s, 4);
    s += __shfl_xor(s, 2);
    s += __shfl_xor(s, 1);
    if (lane == 0) gx2[b*E_ + e] = s;
}

// ---------- K3b: gx2 -> sscale -> w2s fill (fp8), + bc --------------------------
__global__ __launch_bounds__(256) void k3b(
    const float* __restrict__ gx2, const float* __restrict__ gamma,
    const float* __restrict__ w2, const float* __restrict__ beta,
    const float* __restrict__ b2, unsigned char* __restrict__ w2s,
    float* __restrict__ bc)
{
    const int bk = blockIdx.x;
    const int t = threadIdx.x;
    if (bk == 288){
        if (t < 96){
            float a = b2[t];
            for (int e=0;e<E_;++e) a = fmaf(beta[e], w2[e*C_ + t], a);
            bc[t] = a;
        }
        return;
    }
    __shared__ float red[256];
    __shared__ float mean_s;
    const int b = bk / 144;                   // 144*256 = 36864 = C_*E_
    float s = 0.f;
    for (int e = t; e < E_; e += 256)
        s += sqrtf(fmaxf(gx2[b*E_ + e], 0.f));
    red[t] = s;
    __syncthreads();
    if (t < 128) red[t] += red[t+128];
    __syncthreads();
    if (t < 64){
        float v = red[t] + red[t+64];
        v += __shfl_down(v, 32);
        v += __shfl_down(v, 16);
        v += __shfl_down(v, 8);
        v += __shfl_down(v, 4);
        v += __shfl_down(v, 2);
        v += __shfl_down(v, 1);
        if (t == 0) mean_s = v * (1.f/384.f);
    }
    __syncthreads();
    const int idx = bk*256 + t;               // [0, 73728)
    const int rem = idx - b*(C_*E_);
    const int c = rem / E_, e = rem - (rem/E_)*E_;
    float g = sqrtf(fmaxf(gx2[b*E_ + e], 0.f));
    float sc = 1.f + gamma[e] * (g / (mean_s + 1e-6f));
    float val = w2[e*C_ + c] * sc;
    int pk = __builtin_amdgcn_cvt_pk_fp8_f32(val, val, 0, false);
    w2s[idx] = (unsigned char)(pk & 0xff);
}

// ---------- K4: pwconv2 (fp8 MFMA), fragment-ordered fp8 ws2 reads --------------
__global__ __launch_bounds__(256) void k4_pw2(
    const unsigned char* __restrict__ ws2, const unsigned char* __restrict__ w2s,
    const float* __restrict__ bc, const float* __restrict__ x,
    float* __restrict__ out)
{
    const int tid = threadIdx.x;
    const int n0 = blockIdx.x * 128;
    const int b = n0 / S_;
    const int s0 = n0 - b*S_;
    const int lane = tid & 63, q = tid >> 6;
    const int lr = lane & 15, lk = lane >> 4;

    f32x4 acc0[6], acc1[6];
    #pragma unroll
    for (int m=0;m<6;++m){ acc0[m] = (f32x4){0,0,0,0}; acc1[m] = (f32x4){0,0,0,0}; }
    const unsigned char* w2sb = w2s + (size_t)b*C_*E_;
    const unsigned char* base0 = ws2 + (size_t)(blockIdx.x*2)*WS2BLK_
                               + q*6144 + (lr&3)*64 + (lr>>2)*16 + (lk&1)*8;

    for (int kk=0; kk<12; ++kk){
        const int off = (2*kk + (lk>>1))*256;
        long bfr0 = *(const long*)&base0[off];
        long bfr1 = *(const long*)&base0[WS2BLK_ + off];
        #pragma unroll
        for (int m=0;m<6;++m){
            long afr = *(const long*)&w2sb[(size_t)(m*16 + lr)*E_ + kk*32 + lk*8];
            acc0[m] = __builtin_amdgcn_mfma_f32_16x16x32_fp8_fp8(afr, bfr0, acc0[m], 0, 0, 0);
            acc1[m] = __builtin_amdgcn_mfma_f32_16x16x32_fp8_fp8(afr, bfr1, acc1[m], 0, 0, 0);
        }
    }

    const int pos = q*16 + lr;
    const size_t sidx0 = (size_t)s0 + pos;
    #pragma unroll
    for (int m=0;m<6;++m){
        #pragma unroll
        for (int r=0;r<4;++r){
            int c = m*16 + lk*4 + r;
            float bcv = bc[c];
            size_t a0 = ((size_t)(b*C_ + c))*S_ + sidx0;
            out[a0]      = acc0[m][r] + bcv + x[a0];
            out[a0 + 64] = acc1[m][r] + bcv + x[a0 + 64];
        }
    }
}

extern "C" void kernel_launch(void* const* d_in, const int* in_sizes, int n_in,
                              void* d_out, int out_size, void* d_ws, size_t ws_size,
                              hipStream_t stream)
{
    const float* x     = (const float*)d_in[0];
    const float* dwk   = (const float*)d_in[1];
    const float* dwb   = (const float*)d_in[2];
    const float* ln_w  = (const float*)d_in[3];
    const float* ln_b  = (const float*)d_in[4];
    const float* w1    = (const float*)d_in[5];
    const float* b1    = (const float*)d_in[6];
    const float* gamma = (const float*)d_in[7];
    const float* beta  = (const float*)d_in[8];
    const float* w2    = (const float*)d_in[9];
    const float* b2    = (const float*)d_in[10];
    float* out = (float*)d_out;

    char* ws = (char*)d_ws;
    unsigned short* ws1 = (unsigned short*)ws;                        // 28.9 MB used
    unsigned char*  ws2 = (unsigned char*)(ws + 57802752);            // 57.8 MB (fp8)
    unsigned short* w1t = (unsigned short*)(ws + 173408256);          // 73,728 B
    float* bc     = (float*)(ws + 173408256 + 73728);                 // 384 B
    float* gx2    = bc + C_;                                          // 3,072 B
    float* Av     = gx2 + B_*E_;                                      // 1,536 B
    float* Bv     = Av + E_;                                          // 1,536 B
    // aliased into ws1 region (ws1 dead after k2; written after k2):
    unsigned char* w2s = (unsigned char*)ws;                          // 73,728 B (fp8)
    // d_out region as scratch (k4 fully overwrites it afterwards):
    float* partial = (float*)d_out;                                   // 3,612,672 B
    unsigned int* pkwg = (unsigned int*)((char*)d_out + 4194304);     // 131,712 B

    kw1t      <<<dim3(146),     256, 0, stream>>>(w1, dwk, ln_w, ln_b, b1, w1t, pkwg, Av, Bv);
    k1_dwconv <<<dim3(21,96,2), 256, 0, stream>>>(x, pkwg, dwb, ws1);
    k2_ln_pw1 <<<dim3(NBLK_),   256, 0, stream>>>(ws1, w1t, Av, Bv, ws2, partial);
    k3a1      <<<dim3(48,2),    256, 0, stream>>>(partial, gx2);
    k3b       <<<dim3(289),     256, 0, stream>>>(gx2, gamma, w2, beta, b2, w2s, bc);
    k4_pw2    <<<dim3(N_/128),  256, 0, stream>>>(ws2, w2s, bc, x, out);
}

// Round 21
// 279.945 us; speedup vs baseline: 1.0977x; 1.0081x over previous
//
#include <hip/hip_runtime.h>
#include <hip/hip_fp16.h>
#include <stdint.h>

#define B_ 2
#define C_ 96
#define D_ 24
#define H_ 56
#define W_ 56
#define E_ 384
#define HW_ (H_*W_)        // 3136
#define S_ (D_*HW_)        // 75264
#define N_ (B_*S_)         // 150528
#define NBLK_ 2352         // N_/64 (k2 blocks)
#define WS2BLK_ 24576      // BYTES per 64-pos block in fragment-ordered fp8 ws2

typedef __attribute__((ext_vector_type(8))) short bf16x8;
typedef __attribute__((ext_vector_type(4))) float f32x4;
typedef __fp16 fp16x2 __attribute__((ext_vector_type(2)));

static __device__ __forceinline__ float bf2f(unsigned short h){
    union { unsigned int u; float f; } v; v.u = ((unsigned int)h) << 16; return v.f;
}
static __device__ __forceinline__ unsigned short f2bf(float x){
    union { float f; unsigned int u; } v; v.f = x;
    unsigned int r = v.u + 0x7FFFu + ((v.u >> 16) & 1u);
    return (unsigned short)(r >> 16);
}
static __device__ __forceinline__ fp16x2 u2f16(unsigned int u){
    union { unsigned int u; fp16x2 h; } v; v.u = u; return v.h;
}
static __device__ __forceinline__ unsigned int pk_f16(float a, float b){
    union { fp16x2 h; unsigned int u; } v;
    v.h = __builtin_amdgcn_cvt_pkrtz(a, b);
    return v.u;
}
// fast GELU: v*sigmoid(1.5957691*(v+0.044715 v^3)) via exp2, max |err| ~3e-4
static __device__ __forceinline__ float gelu_f(float v){
    float v2 = v*v;
    float arg = v * fmaf(v2, -0.1029432f, -2.3022080f);
    return v / (1.f + exp2f(arg));
}

// ---------------- K1 (converged): dw conv 8d x 8h x 56w -> ws1 ------------------
__global__ __launch_bounds__(256) void k1_dwconv(
    const float* __restrict__ x, const unsigned int* __restrict__ pkwg,
    const float* __restrict__ bias, unsigned short* __restrict__ ws1)
{
    __shared__ __align__(16) unsigned short hl[14*14*72];
    const int dt = blockIdx.x / 7;   // 0..2
    const int ht = blockIdx.x - dt*7;// 0..6
    const int c  = blockIdx.y, b = blockIdx.z;
    const int d0 = dt*8, h0 = ht*8;
    const int tid = threadIdx.x;
    const float* xc = x + (size_t)(b*C_ + c) * S_;
    const unsigned int* pw = pkwg + c*343;   // block-uniform -> s_load

    for (int i = tid; i < 14*14*31; i += 256){
        int sidx = i / (14*31);
        int rem  = i - sidx*(14*31);
        int hr   = rem / 31;
        int wp   = rem - hr*31;
        int d = d0 - 3 + sidx, h = h0 - 3 + hr, w = wp*2 - 3;
        bool ok = (unsigned)d < D_ && (unsigned)h < H_;
        float v0 = (ok && (unsigned)w     < W_) ? xc[d*HW_ + h*W_ + w]   : 0.f;
        float v1 = (ok && (unsigned)(w+1) < W_) ? xc[d*HW_ + h*W_ + w+1] : 0.f;
        *(unsigned int*)&hl[(sidx*14 + hr)*72 + wp*2] = pk_f16(v0, v1);
    }
    __syncthreads();

    const int wz = tid & 7, hz = (tid >> 3) & 7, dz = tid >> 6;
    if (wz >= 7) return;

    fp16x2 acc0[4], acc1[4];
    #pragma unroll
    for (int r=0;r<4;++r){ acc0[r] = u2f16(0u); acc1[r] = u2f16(0u); }

    for (int kh = 0; kh < 7; ++kh){
        unsigned int wprev[7];
        for (int si = 0; si < 8; ++si){
            const unsigned short* rp = &hl[((dz*2 + si)*14 + hz + kh)*72 + wz*8];
            uint4 wa = *(const uint4*)rp;
            uint2 wb = *(const uint2*)(rp + 8);
            unsigned int wcq = *(const unsigned int*)(rp + 12);
            unsigned int W[7] = {wa.x, wa.y, wa.z, wa.w, wb.x, wb.y, wcq};
            unsigned int Sh[6];
            #pragma unroll
            for (int m=0;m<6;++m) Sh[m] = __builtin_amdgcn_alignbit(W[m+1], W[m], 16);

            if (si < 7){
                unsigned int wcur[7];
                #pragma unroll
                for (int k=0;k<7;++k) wcur[k] = pw[si*49 + kh*7 + k];
                #pragma unroll
                for (int kw=0; kw<7; ++kw){
                    const int m = kw >> 1;
                    fp16x2 wp = u2f16(wcur[kw]);
                    #pragma unroll
                    for (int r=0;r<4;++r){
                        fp16x2 src = (kw & 1) ? u2f16(Sh[m+r]) : u2f16(W[m+r]);
                        acc0[r] = __builtin_elementwise_fma(src, wp, acc0[r]);
                    }
                }
                if (si > 0){
                    #pragma unroll
                    for (int kw=0; kw<7; ++kw){
                        const int m = kw >> 1;
                        fp16x2 wp = u2f16(wprev[kw]);
                        #pragma unroll
                        for (int r=0;r<4;++r){
                            fp16x2 src = (kw & 1) ? u2f16(Sh[m+r]) : u2f16(W[m+r]);
                            acc1[r] = __builtin_elementwise_fma(src, wp, acc1[r]);
                        }
                    }
                }
                #pragma unroll
                for (int k=0;k<7;++k) wprev[k] = wcur[k];
            } else {
                #pragma unroll
                for (int kw=0; kw<7; ++kw){
                    const int m = kw >> 1;
                    fp16x2 wp = u2f16(wprev[kw]);
                    #pragma unroll
                    for (int r=0;r<4;++r){
                        fp16x2 src = (kw & 1) ? u2f16(Sh[m+r]) : u2f16(W[m+r]);
                        acc1[r] = __builtin_elementwise_fma(src, wp, acc1[r]);
                    }
                }
            }
        }
    }

    const float bs = bias[c];
    float o0v[8], o1v[8];
    #pragma unroll
    for (int r=0;r<4;++r){
        o0v[2*r]   = (float)acc0[r][0] + bs;
        o0v[2*r+1] = (float)acc0[r][1] + bs;
        o1v[2*r]   = (float)acc1[r][0] + bs;
        o1v[2*r+1] = (float)acc1[r][1] + bs;
    }
    size_t o0 = (size_t)(b*C_ + c)*S_ + (size_t)(d0 + dz*2)*HW_ + (h0 + hz)*W_ + wz*8;
    unsigned int p0 = (unsigned)f2bf(o0v[0]) | ((unsigned)f2bf(o0v[1])<<16);
    unsigned int p1 = (unsigned)f2bf(o0v[2]) | ((unsigned)f2bf(o0v[3])<<16);
    unsigned int p2 = (unsigned)f2bf(o0v[4]) | ((unsigned)f2bf(o0v[5])<<16);
    unsigned int p3 = (unsigned)f2bf(o0v[6]) | ((unsigned)f2bf(o0v[7])<<16);
    *(uint4*)&ws1[o0] = make_uint4(p0,p1,p2,p3);
    p0 = (unsigned)f2bf(o1v[0]) | ((unsigned)f2bf(o1v[1])<<16);
    p1 = (unsigned)f2bf(o1v[2]) | ((unsigned)f2bf(o1v[3])<<16);
    p2 = (unsigned)f2bf(o1v[4]) | ((unsigned)f2bf(o1v[5])<<16);
    p3 = (unsigned)f2bf(o1v[6]) | ((unsigned)f2bf(o1v[7])<<16);
    *(uint4*)&ws1[o0 + HW_] = make_uint4(p0,p1,p2,p3);
}

// ---------- kw1t: w1t[e][c] = bf16(ln_w[c]*w1[c,e]); pkwg; A,B vectors ----------
__global__ __launch_bounds__(256) void kw1t(
    const float* __restrict__ w1, const float* __restrict__ wk,
    const float* __restrict__ ln_w, const float* __restrict__ ln_b,
    const float* __restrict__ b1, unsigned short* __restrict__ w1t,
    unsigned int* __restrict__ pkwg, float* __restrict__ Av, float* __restrict__ Bv)
{
    int bk = blockIdx.x;
    if (bk >= 144){
        int e = (bk - 144)*256 + threadIdx.x;
        if (e < E_){
            float a = 0.f, bb = b1[e];
            for (int c=0;c<C_;++c){
                float w = w1[c*E_ + e];
                a  = fmaf(ln_w[c], w, a);
                bb = fmaf(ln_b[c], w, bb);
            }
            Av[e] = a; Bv[e] = bb;
        }
        return;
    }
    int idx = bk*256 + threadIdx.x;
    if (idx < E_*C_){
        int e = idx / C_, c = idx % C_;
        w1t[idx] = f2bf(w1[c*E_ + e] * ln_w[c]);
    }
    if (idx < 96*343){
        unsigned short us = __half_as_ushort(__float2half(wk[idx]));
        pkwg[idx] = (unsigned)us | ((unsigned)us << 16);
    }
}

// ------------- K2 v2: in-register LN + pwconv1(MFMA) + GELU -> ws2 fp8 ----------
// A-fragments loaded DIRECT from ws1 (no ly LDS tile, no LN barrier).
// lane (lr,lk) holds positions row=q*16+lr, c = kk*32+lk*8+j.
__global__ __launch_bounds__(256) void k2_ln_pw1(
    const unsigned short* __restrict__ ws1, const unsigned short* __restrict__ w1t,
    const float* __restrict__ Av, const float* __restrict__ Bv,
    unsigned char* __restrict__ ws2, float* __restrict__ partial)
{
    __shared__ float sq[4][384];
    __shared__ float As[384], Bs[384];
    const int tid = threadIdx.x;
    const int q = tid >> 6;
    const int lane = tid & 63;
    const int lr = lane & 15;
    const int lk = lane >> 4;
    const int n0 = blockIdx.x * 64;
    const int b = n0 / S_;
    const int s0 = n0 - b*S_;

    for (int i = tid; i < 384; i += 256){ As[i] = Av[i]; Bs[i] = Bv[i]; }

    // direct fragment loads: af[kk][j] = ws1[(b*C + kk*32+lk*8+j)*S + s0 + q*16 + lr]
    const unsigned short* src = ws1 + (size_t)(b*C_ + lk*8)*S_ + s0 + q*16 + lr;
    unsigned short uv[24];
    float sum=0.f, ssq=0.f;
    #pragma unroll
    for (int kk=0;kk<3;++kk){
        #pragma unroll
        for (int j=0;j<8;++j){
            unsigned short u = src[(size_t)(kk*32 + j)*S_];
            uv[kk*8+j] = u;
            float t = bf2f(u);
            sum += t; ssq = fmaf(t,t,ssq);
        }
    }
    // cross-lk reduce (lanes lr fixed, lk 0..3): full 96-channel sums
    sum += __shfl_xor(sum, 16);  ssq += __shfl_xor(ssq, 16);
    sum += __shfl_xor(sum, 32);  ssq += __shfl_xor(ssq, 32);
    float mu = sum * (1.f/96.f);
    float var = ssq*(1.f/96.f) - mu*mu;
    float rs = rsqrtf(var + 1e-6f);     // valid for position q*16+lr (all lk dup)
    float rm = -rs*mu;

    // pack fragments
    bf16x8 af[3];
    #pragma unroll
    for (int kk=0;kk<3;++kk){
        unsigned int w0 = (unsigned)uv[kk*8+0] | ((unsigned)uv[kk*8+1]<<16);
        unsigned int w1p= (unsigned)uv[kk*8+2] | ((unsigned)uv[kk*8+3]<<16);
        unsigned int w2p= (unsigned)uv[kk*8+4] | ((unsigned)uv[kk*8+5]<<16);
        unsigned int w3 = (unsigned)uv[kk*8+6] | ((unsigned)uv[kk*8+7]<<16);
        union { uint4 u; bf16x8 v; } cv; cv.u = make_uint4(w0,w1p,w2p,w3);
        af[kk] = cv.v;
    }

    // redistribute rs,rm for the D-frag rows pos = q*16 + lk*4 + r (source lane lk*4+r)
    float rsv[4], rmv[4];
    #pragma unroll
    for (int r=0;r<4;++r){
        rsv[r] = __shfl(rs, lk*4 + r);
        rmv[r] = __shfl(rm, lk*4 + r);
    }

    unsigned char* wout = ws2 + (size_t)blockIdx.x*WS2BLK_ + q*6144 + lane;

    for (int nt=0; nt<24; ++nt){
        f32x4 acc = {0.f,0.f,0.f,0.f};
        #pragma unroll
        for (int kk=0;kk<3;++kk){
            bf16x8 bfr = *(const bf16x8*)&w1t[(size_t)(nt*16 + lr)*C_ + kk*32 + lk*8];
            acc = __builtin_amdgcn_mfma_f32_16x16x32_bf16(af[kk], bfr, acc, 0, 0, 0);
        }
        float Ae = As[nt*16 + lr];
        float Be = Bs[nt*16 + lr];
        float gv[4];
        float ps = 0.f;
        #pragma unroll
        for (int r=0;r<4;++r){
            float val = fmaf(rsv[r], acc[r], fmaf(rmv[r], Ae, Be));
            float g = gelu_f(val);
            gv[r] = g;
            ps = fmaf(g,g,ps);
        }
        int pk = __builtin_amdgcn_cvt_pk_fp8_f32(gv[0], gv[1], 0, false);
        pk     = __builtin_amdgcn_cvt_pk_fp8_f32(gv[2], gv[3], pk, true);
        unsigned char* wb = wout + nt*256;
        wb[0]   = (unsigned char)( pk        & 0xff);
        wb[64]  = (unsigned char)((pk >> 8)  & 0xff);
        wb[128] = (unsigned char)((pk >> 16) & 0xff);
        wb[192] = (unsigned char)((pk >> 24) & 0xff);
        ps += __shfl_xor(ps, 16);
        ps += __shfl_xor(ps, 32);
        if (lane < 16) sq[q][nt*16 + lane] = ps;
    }
    __syncthreads();
    for (int i = tid; i < 384; i += 256)
        partial[(size_t)i*NBLK_ + blockIdx.x] = sq[0][i]+sq[1][i]+sq[2][i]+sq[3][i];
}

// ---------- K3a1: parallel reduce partial[e][NBLK_] -> gx2[b][e] ----------------
__global__ __launch_bounds__(256) void k3a1(
    const float* __restrict__ partial, float* __restrict__ gx2)
{
    const int g = blockIdx.x, b = blockIdx.y;
    const int t = threadIdx.x;
    const int el = t >> 5, lane = t & 31;
    const int e = g*8 + el;
    const float4* row = (const float4*)(partial + (size_t)e*NBLK_ + b*(NBLK_/2));
    float s = 0.f;
    for (int k = lane; k < 294; k += 32){
        float4 v = row[k];
        s += v.x + v.y + v.z + v.w;
    }
    s += __shfl_xor(s, 16);
    s += __shfl_xor(s, 8);
    s += __shfl_xor(s, 4);
    s += __shfl_xor(s, 2);
    s += __shfl_xor(s, 1);
    if (lane == 0) gx2[b*E_ + e] = s;
}

// ---------- K3b: gx2 -> sscale -> w2s fill (fp8), + bc --------------------------
__global__ __launch_bounds__(256) void k3b(
    const float* __restrict__ gx2, const float* __restrict__ gamma,
    const float* __restrict__ w2, const float* __restrict__ beta,
    const float* __restrict__ b2, unsigned char* __restrict__ w2s,
    float* __restrict__ bc)
{
    const int bk = blockIdx.x;
    const int t = threadIdx.x;
    if (bk == 288){
        if (t < 96){
            float a = b2[t];
            for (int e=0;e<E_;++e) a = fmaf(beta[e], w2[e*C_ + t], a);
            bc[t] = a;
        }
        return;
    }
    __shared__ float red[256];
    __shared__ float mean_s;
    const int b = bk / 144;                   // 144*256 = 36864 = C_*E_
    float s = 0.f;
    for (int e = t; e < E_; e += 256)
        s += sqrtf(fmaxf(gx2[b*E_ + e], 0.f));
    red[t] = s;
    __syncthreads();
    if (t < 128) red[t] += red[t+128];
    __syncthreads();
    if (t < 64){
        float v = red[t] + red[t+64];
        v += __shfl_down(v, 32);
        v += __shfl_down(v, 16);
        v += __shfl_down(v, 8);
        v += __shfl_down(v, 4);
        v += __shfl_down(v, 2);
        v += __shfl_down(v, 1);
        if (t == 0) mean_s = v * (1.f/384.f);
    }
    __syncthreads();
    const int idx = bk*256 + t;               // [0, 73728)
    const int rem = idx - b*(C_*E_);
    const int c = rem / E_, e = rem - (rem/E_)*E_;
    float g = sqrtf(fmaxf(gx2[b*E_ + e], 0.f));
    float sc = 1.f + gamma[e] * (g / (mean_s + 1e-6f));
    float val = w2[e*C_ + c] * sc;
    int pk = __builtin_amdgcn_cvt_pk_fp8_f32(val, val, 0, false);
    w2s[idx] = (unsigned char)(pk & 0xff);
}

// ---------- K4: pwconv2 (fp8 MFMA), fragment-ordered fp8 ws2 reads --------------
__global__ __launch_bounds__(256) void k4_pw2(
    const unsigned char* __restrict__ ws2, const unsigned char* __restrict__ w2s,
    const float* __restrict__ bc, const float* __restrict__ x,
    float* __restrict__ out)
{
    const int tid = threadIdx.x;
    const int n0 = blockIdx.x * 128;
    const int b = n0 / S_;
    const int s0 = n0 - b*S_;
    const int lane = tid & 63, q = tid >> 6;
    const int lr = lane & 15, lk = lane >> 4;

    f32x4 acc0[6], acc1[6];
    #pragma unroll
    for (int m=0;m<6;++m){ acc0[m] = (f32x4){0,0,0,0}; acc1[m] = (f32x4){0,0,0,0}; }
    const unsigned char* w2sb = w2s + (size_t)b*C_*E_;
    const unsigned char* base0 = ws2 + (size_t)(blockIdx.x*2)*WS2BLK_
                               + q*6144 + (lr&3)*64 + (lr>>2)*16 + (lk&1)*8;

    for (int kk=0; kk<12; ++kk){
        const int off = (2*kk + (lk>>1))*256;
        long bfr0 = *(const long*)&base0[off];
        long bfr1 = *(const long*)&base0[WS2BLK_ + off];
        #pragma unroll
        for (int m=0;m<6;++m){
            long afr = *(const long*)&w2sb[(size_t)(m*16 + lr)*E_ + kk*32 + lk*8];
            acc0[m] = __builtin_amdgcn_mfma_f32_16x16x32_fp8_fp8(afr, bfr0, acc0[m], 0, 0, 0);
            acc1[m] = __builtin_amdgcn_mfma_f32_16x16x32_fp8_fp8(afr, bfr1, acc1[m], 0, 0, 0);
        }
    }

    const int pos = q*16 + lr;
    const size_t sidx0 = (size_t)s0 + pos;
    #pragma unroll
    for (int m=0;m<6;++m){
        #pragma unroll
        for (int r=0;r<4;++r){
            int c = m*16 + lk*4 + r;
            float bcv = bc[c];
            size_t a0 = ((size_t)(b*C_ + c))*S_ + sidx0;
            out[a0]      = acc0[m][r] + bcv + x[a0];
            out[a0 + 64] = acc1[m][r] + bcv + x[a0 + 64];
        }
    }
}

extern "C" void kernel_launch(void* const* d_in, const int* in_sizes, int n_in,
                              void* d_out, int out_size, void* d_ws, size_t ws_size,
                              hipStream_t stream)
{
    const float* x     = (const float*)d_in[0];
    const float* dwk   = (const float*)d_in[1];
    const float* dwb   = (const float*)d_in[2];
    const float* ln_w  = (const float*)d_in[3];
    const float* ln_b  = (const float*)d_in[4];
    const float* w1    = (const float*)d_in[5];
    const float* b1    = (const float*)d_in[6];
    const float* gamma = (const float*)d_in[7];
    const float* beta  = (const float*)d_in[8];
    const float* w2    = (const float*)d_in[9];
    const float* b2    = (const float*)d_in[10];
    float* out = (float*)d_out;

    char* ws = (char*)d_ws;
    unsigned short* ws1 = (unsigned short*)ws;                        // 28.9 MB used
    unsigned char*  ws2 = (unsigned char*)(ws + 57802752);            // 57.8 MB (fp8)
    unsigned short* w1t = (unsigned short*)(ws + 173408256);          // 73,728 B
    float* bc     = (float*)(ws + 173408256 + 73728);                 // 384 B
    float* gx2    = bc + C_;                                          // 3,072 B
    float* Av     = gx2 + B_*E_;                                      // 1,536 B
    float* Bv     = Av + E_;                                          // 1,536 B
    // aliased into ws1 region (ws1 dead after k2; written after k2):
    unsigned char* w2s = (unsigned char*)ws;                          // 73,728 B (fp8)
    // d_out region as scratch (k4 fully overwrites it afterwards):
    float* partial = (float*)d_out;                                   // 3,612,672 B
    unsigned int* pkwg = (unsigned int*)((char*)d_out + 4194304);     // 131,712 B

    kw1t      <<<dim3(146),     256, 0, stream>>>(w1, dwk, ln_w, ln_b, b1, w1t, pkwg, Av, Bv);
    k1_dwconv <<<dim3(21,96,2), 256, 0, stream>>>(x, pkwg, dwb, ws1);
    k2_ln_pw1 <<<dim3(NBLK_),   256, 0, stream>>>(ws1, w1t, Av, Bv, ws2, partial);
    k3a1      <<<dim3(48,2),    256, 0, stream>>>(partial, gx2);
    k3b       <<<dim3(289),     256, 0, stream>>>(gx2, gamma, w2, beta, b2, w2s, bc);
    k4_pw2    <<<dim3(N_/128),  256, 0, stream>>>(ws2, w2s, bc, x, out);
}